// Round 5
// baseline (435.793 us; speedup 1.0000x reference)
//
#include <hip/hip_runtime.h>
#include <hip/hip_cooperative_groups.h>
#include <math.h>

namespace cg = cooperative_groups;

typedef unsigned long long u64;

#define NBATCH 2
#define LTOK 196
#define DDIM 768
#define NROWS (NBATCH*LTOK)      // 392
#define NLD (NBATCH*LTOK*DDIM)   // 301056
#define GRID 512                 // 2 blocks/CU on 256 CUs -- co-resident for coop launch

#define PI_F 3.14159265358979323846f
#define S3 0.86602540378443864676f   // sqrt(3)/2

// combine tiling: 2(a) x 14(i-tile of 14) x 3(d-chunk of 256) x 4(j-chunk of 49) = 336 tasks
#define RT 14
#define JCH 4
#define JLEN 49

// ---------------------------------------------------------------------------
// Phase-union'd LDS (max member: greedy = 12564 B)
// ---------------------------------------------------------------------------
union SMem {
  struct { float re[768]; float im[768]; float2 t256[128]; } fft;     // 7168 B
  struct { float ui[768]; u64 mask[4]; } sim;                          // 3104 B
  struct { u64 Ml[NROWS * 4]; int red[4]; int done; } greedy;          // 12564 B
  struct { u64 mrow[4]; } stats;                                       // 32 B
  struct { float lsr[RT][JLEN]; float lnr[RT][JLEN]; } comb;           // 5488 B
  struct { double rs[4], rq[4]; float mu, sc; } patch;                 // 72 B
};

// ---------------------------------------------------------------------------
// FFT768 = 3 x FFT256 (radix-2 DIT, bit-reversed in-place) + radix-3 combine.
// ---------------------------------------------------------------------------
__device__ __forceinline__ void fft_butterfly(float* re, float* im,
                                              const float2* T,
                                              int tau, int s, int half) {
  int sub = tau >> 7;            // 0..2
  int b = tau & 127;
  int j = b & (half - 1);
  int p0 = (sub << 8) + ((b >> (s - 1)) << s) + j;
  int p1 = p0 + half;
  float2 w = T[j << (8 - s)];
  float xr = re[p1], xi = im[p1];
  float tr = w.x * xr - w.y * xi;
  float ti = w.x * xi + w.y * xr;
  float ur = re[p0], ui = im[p0];
  re[p0] = ur + tr; im[p0] = ui + ti;
  re[p1] = ur - tr; im[p1] = ui - ti;
}

__device__ __forceinline__ void fft_stages(float* re, float* im,
                                           const float2* T, int t) {
#pragma unroll
  for (int s = 1; s <= 8; s++) {
    int half = 1 << (s - 1);
    fft_butterfly(re, im, T, t, s, half);
    if (t < 128) fft_butterfly(re, im, T, t + 256, s, half);
    __syncthreads();
  }
}

// ---------------------------------------------------------------------------
// The whole pipeline as one cooperative kernel with 5 grid barriers.
// ---------------------------------------------------------------------------
__global__ __launch_bounds__(256, 2) void k_mono(const float* __restrict__ imgs,
                                                 const float* __restrict__ x,
                                                 const float* __restrict__ ls,
                                                 const float* __restrict__ nz,
                                                 float* __restrict__ out,
                                                 float* __restrict__ uT,
                                                 float* __restrict__ sty,
                                                 float* __restrict__ phre,
                                                 float* __restrict__ phim,
                                                 float* __restrict__ sstd,
                                                 float* __restrict__ smsk,
                                                 float* __restrict__ numP,
                                                 float* __restrict__ denP,
                                                 u64* __restrict__ Mb) {
  cg::grid_group grid = cg::this_grid();
  __shared__ SMem sm;
  int t = threadIdx.x;

  // ========== Phase 1: patchify (tasks 0..391) + forward FFT (392..783) ====
  for (int task = blockIdx.x; task < 2 * NROWS; task += GRID) {
    if (task < NROWS) {
      int a = task / LTOK, l = task - a * LTOK;
      int hh = l / 14, ww = l - hh * 14;
      float loc[3];
      double s = 0.0, sq = 0.0;
#pragma unroll
      for (int e = 0; e < 3; e++) {
        int d = t + (e << 8);
        int p = d / 48, r = d - p * 48;
        int q2 = r / 3, c = r - q2 * 3;
        float val = imgs[((size_t)(a * 3 + c) * 224 + (hh * 16 + p)) * 224 + (ww * 16 + q2)];
        loc[e] = val;
        s += (double)val;
        sq += (double)val * (double)val;
      }
#pragma unroll
      for (int o = 32; o > 0; o >>= 1) { s += __shfl_down(s, o); sq += __shfl_down(sq, o); }
      if ((t & 63) == 0) { sm.patch.rs[t >> 6] = s; sm.patch.rq[t >> 6] = sq; }
      __syncthreads();
      if (t == 0) {
        double S = sm.patch.rs[0] + sm.patch.rs[1] + sm.patch.rs[2] + sm.patch.rs[3];
        double Q = sm.patch.rq[0] + sm.patch.rq[1] + sm.patch.rq[2] + sm.patch.rq[3];
        double mean = S / 768.0;
        double ss = Q - S * S / 768.0;
        if (ss < 1e-30) ss = 1e-30;
        sm.patch.mu = (float)mean;
        sm.patch.sc = (float)(1.0 / sqrt(ss));
      }
      __syncthreads();
      float mu = sm.patch.mu, sc = sm.patch.sc;
      int col = a * LTOK + l;
#pragma unroll
      for (int e = 0; e < 3; e++) {
        int d = t + (e << 8);
        uT[(size_t)d * NROWS + col] = (loc[e] - mu) * sc;
      }
    } else {
      int blk = task - NROWS;
      int a = blk / LTOK, i = blk - a * LTOK;
      if (t < 128) {
        float sn, cs;
        __sincosf(-2.0f * PI_F * (float)t / 256.0f, &sn, &cs);
        sm.fft.t256[t] = make_float2(cs, sn);
      }
      size_t row = ((size_t)a * (LTOK + 1) + 1 + i) * DDIM;
#pragma unroll
      for (int e = 0; e < 3; e++) {
        int d = t + (e << 8);
        int m = d / 3, r = d - 3 * m;          // decimate n = 3m + r
        int p = (r << 8) + (__brev((unsigned)m) >> 24);
        sm.fft.re[p] = x[row + d];
        sm.fft.im[p] = 0.f;
      }
      __syncthreads();
      fft_stages(sm.fft.re, sm.fft.im, sm.fft.t256, t);
      float a0r = sm.fft.re[t],       a0i = sm.fft.im[t];
      float a1r = sm.fft.re[256 + t], a1i = sm.fft.im[256 + t];
      float a2r = sm.fft.re[512 + t], a2i = sm.fft.im[512 + t];
      float sn, cs;
      __sincosf(-2.0f * PI_F * (float)t / 768.0f, &sn, &cs);
      float2 w1 = make_float2(cs, sn);
      float2 w2 = make_float2(cs * cs - sn * sn, 2.f * cs * sn);
      float b1r = a1r * w1.x - a1i * w1.y, b1i = a1r * w1.y + a1i * w1.x;
      float b2r = a2r * w2.x - a2i * w2.y, b2i = a2r * w2.y + a2i * w2.x;
      float Xr[3], Xi[3];
      Xr[0] = a0r + b1r + b2r;
      Xi[0] = a0i + b1i + b2i;
      Xr[1] = a0r + (-0.5f * b1r + S3 * b1i) + (-0.5f * b2r - S3 * b2i);
      Xi[1] = a0i + (-0.5f * b1i - S3 * b1r) + (-0.5f * b2i + S3 * b2r);
      Xr[2] = a0r + (-0.5f * b1r - S3 * b1i) + (-0.5f * b2r + S3 * b2i);
      Xi[2] = a0i + (-0.5f * b1i + S3 * b1r) + (-0.5f * b2i - S3 * b2r);
      size_t ob = ((size_t)a * LTOK + i) * DDIM + t;
#pragma unroll
      for (int s = 0; s < 3; s++) {
        float mag = sqrtf(Xr[s] * Xr[s] + Xi[s] * Xi[s]);
        size_t o = ob + (s << 8);
        sty[o] = mag;
        if (mag > 0.f) { phre[o] = Xr[s] / mag; phim[o] = Xi[s] / mag; }
        else           { phre[o] = 1.f;         phim[o] = 0.f;         }
      }
    }
    __syncthreads();
  }
  grid.sync();

  // ========== Phase 2: Sim row i vs j>=i, bitmask M0 =======================
  for (int task = blockIdx.x; task < NROWS; task += GRID) {
    int a = task / LTOK, i = task - a * LTOK;
    if (t < 4) sm.sim.mask[t] = 0ull;
    int coli = a * LTOK + i;
#pragma unroll
    for (int e = 0; e < 3; e++) {
      int d = t + (e << 8);
      sm.sim.ui[d] = uT[(size_t)d * NROWS + coli];
    }
    __syncthreads();
    int j = i + t;
    if (j < LTOK) {
      const float* col = uT + (a * LTOK + j);
      float dot = 0.f;
#pragma unroll 8
      for (int d = 0; d < 768; d++) dot += sm.sim.ui[d] * col[(size_t)d * NROWS];
      if (dot > 0.3f) atomicOr(&sm.sim.mask[j >> 6], 1ull << (j & 63));
    }
    __syncthreads();
    if (t < 4) Mb[((size_t)a * LTOK + i) * 4 + t] = sm.sim.mask[t];
    __syncthreads();
  }
  grid.sync();

  // ========== Phase 3: sequential greedy with done-freeze (block 0) ========
  if (blockIdx.x == 0) {
    for (int w = t; w < NROWS * 4; w += 256) sm.greedy.Ml[w] = Mb[w];
    __syncthreads();
    for (int i = 0; i < LTOK - 1; i++) {
      int s = 0;
      for (int w = t; w < NROWS * 4; w += 256) s += __popcll(sm.greedy.Ml[w]);
#pragma unroll
      for (int o = 32; o > 0; o >>= 1) s += __shfl_down(s, o);
      if ((t & 63) == 0) sm.greedy.red[t >> 6] = s;
      __syncthreads();
      if (t == 0)
        sm.greedy.done = ((sm.greedy.red[0] + sm.greedy.red[1] +
                           sm.greedy.red[2] + sm.greedy.red[3]) == NROWS) ? 1 : 0;
      __syncthreads();
      if (sm.greedy.done) break;
      for (int w = t; w < NROWS * 4; w += 256) {
        int a = w / (LTOK * 4);
        int rem = w - a * (LTOK * 4);
        int r = rem >> 2, wi = rem & 3;
        if (r > i) sm.greedy.Ml[w] &= ~sm.greedy.Ml[(a * LTOK + i) * 4 + wi];
      }
      __syncthreads();
    }
    for (int w = t; w < NROWS * 4; w += 256) Mb[w] = sm.greedy.Ml[w];
  }
  grid.sync();

  // ========== Phase 4: masked stats per row (two-pass std) =================
  for (int task = blockIdx.x; task < NROWS; task += GRID) {
    int a = task / LTOK, i = task - a * LTOK;
    if (t < 4) sm.stats.mrow[t] = Mb[((size_t)a * LTOK + i) * 4 + t];
    __syncthreads();
    u64 m0 = sm.stats.mrow[0], m1 = sm.stats.mrow[1],
        m2 = sm.stats.mrow[2], m3 = sm.stats.mrow[3];
    int num = __popcll(m0) + __popcll(m1) + __popcll(m2) + __popcll(m3);
    float fnum = fmaxf((float)num, 1e-7f);
    float acc0 = 0.f, acc1 = 0.f, acc2 = 0.f;
    u64 mr[4] = {m0, m1, m2, m3};
    for (int w = 0; w < 4; w++) {
      u64 m = mr[w];
      while (m) {
        int b = __ffsll(m) - 1; m &= (m - 1);
        int j = (w << 6) + b;
        const float* sr = sty + ((size_t)a * LTOK + j) * DDIM;
        acc0 += sr[t]; acc1 += sr[t + 256]; acc2 += sr[t + 512];
      }
    }
    float av0 = acc0 / fnum, av1 = acc1 / fnum, av2 = acc2 / fnum;
    float sq0 = 0.f, sq1 = 0.f, sq2 = 0.f;
    for (int w = 0; w < 4; w++) {
      u64 m = mr[w];
      while (m) {
        int b = __ffsll(m) - 1; m &= (m - 1);
        int j = (w << 6) + b;
        const float* sr = sty + ((size_t)a * LTOK + j) * DDIM;
        float d0 = sr[t] - av0, d1 = sr[t + 256] - av1, d2 = sr[t + 512] - av2;
        sq0 += d0 * d0; sq1 += d1 * d1; sq2 += d2 * d2;
      }
    }
    size_t o = ((size_t)a * LTOK + i) * DDIM + t;
    float mk0 = acc0 > 0.f ? 1.f : 0.f;
    float mk1 = acc1 > 0.f ? 1.f : 0.f;
    float mk2 = acc2 > 0.f ? 1.f : 0.f;
    smsk[o] = mk0;            smsk[o + 256] = mk1;            smsk[o + 512] = mk2;
    // savg aliases uT's buffer slot? NO — separate buffer; uT still needed? not after phase 2.
    // We write avg into a dedicated region (passed as numP's tail? keep separate buffer savg==uT).
    uT[o] = mk0 * av0;        uT[o + 256] = mk1 * av1;        uT[o + 512] = mk2 * av2;
    sstd[o] = mk0 * sqrtf(sq0 / fnum);
    sstd[o + 256] = mk1 * sqrtf(sq1 / fnum);
    sstd[o + 512] = mk2 * sqrtf(sq2 / fnum);
  }
  grid.sync();

  // ========== Phase 5: combine partials (336 tasks) ========================
  for (int task = blockIdx.x; task < NBATCH * RT * 3 * JCH; task += GRID) {
    int a = task / 168;
    int rem = task - a * 168;
    int it = rem / 12;
    int r2 = rem - it * 12;
    int dc = r2 >> 2;
    int jc = r2 & 3;
    int i0 = it * RT;
    int j0 = jc * JLEN;
    int d = (dc << 8) + t;
    for (int idx = t; idx < RT * JLEN; idx += 256) {
      int ii = idx / JLEN, j = idx - ii * JLEN;
      size_t o = ((size_t)(a * LTOK + i0 + ii)) * LTOK + j0 + j;
      float l = ls[o];
      sm.comb.lsr[ii][j] = l;
      sm.comb.lnr[ii][j] = l * nz[o];
    }
    __syncthreads();
    float nm[RT], dn[RT];
#pragma unroll
    for (int ii = 0; ii < RT; ii++) { nm[ii] = 0.f; dn[ii] = 0.f; }
#pragma unroll 7
    for (int j = 0; j < JLEN; j++) {
      size_t b = ((size_t)(a * LTOK + j0 + j)) * DDIM + d;
      float sd = sstd[b], sv = uT[b], smv = smsk[b];
#pragma unroll
      for (int ii = 0; ii < RT; ii++) {
        nm[ii] += sm.comb.lnr[ii][j] * sd;
        nm[ii] += sm.comb.lsr[ii][j] * sv;
        dn[ii] += sm.comb.lsr[ii][j] * smv;
      }
    }
#pragma unroll
    for (int ii = 0; ii < RT; ii++) {
      size_t o = ((size_t)jc * NROWS + (a * LTOK + i0 + ii)) * DDIM + d;
      numP[o] = nm[ii];
      denP[o] = dn[ii];
    }
    __syncthreads();
  }
  grid.sync();

  // ========== Phase 6: reduce partials -> inverse FFT -> out (+cls) ========
  for (int task = blockIdx.x; task < NBATCH + NROWS; task += GRID) {
    if (task < NBATCH) {
      size_t b = (size_t)task * (LTOK + 1) * DDIM;
      out[b + t] = x[b + t];
      out[b + t + 256] = x[b + t + 256];
      out[b + t + 512] = x[b + t + 512];
      __syncthreads();
      continue;
    }
    int rr = task - NBATCH;
    int a = rr / LTOK, i = rr - a * LTOK;
    if (t < 128) {
      float sn, cs;
      __sincosf(2.0f * PI_F * (float)t / 256.0f, &sn, &cs);
      sm.fft.t256[t] = make_float2(cs, sn);
    }
    size_t rowz = ((size_t)a * LTOK + i) * DDIM;
#pragma unroll
    for (int e = 0; e < 3; e++) {
      int d = t + (e << 8);
      float num = 0.f, den = 0.f;
#pragma unroll
      for (int jc = 0; jc < JCH; jc++) {
        size_t o = (size_t)jc * NROWS * DDIM + rowz + d;
        num += numP[o];
        den += denP[o];
      }
      float mg = num / fmaxf(den, 1e-7f);
      int m = d / 3, r = d - 3 * m;          // decimate k = 3m + r
      int p = (r << 8) + (__brev((unsigned)m) >> 24);
      sm.fft.re[p] = mg * phre[rowz + d];
      sm.fft.im[p] = mg * phim[rowz + d];
    }
    __syncthreads();
    fft_stages(sm.fft.re, sm.fft.im, sm.fft.t256, t);
    float a0r = sm.fft.re[t],       a0i = sm.fft.im[t];
    float a1r = sm.fft.re[256 + t], a1i = sm.fft.im[256 + t];
    float a2r = sm.fft.re[512 + t], a2i = sm.fft.im[512 + t];
    float sn, cs;
    __sincosf(2.0f * PI_F * (float)t / 768.0f, &sn, &cs);
    float2 w1 = make_float2(cs, sn);
    float2 w2 = make_float2(cs * cs - sn * sn, 2.f * cs * sn);
    float b1r = a1r * w1.x - a1i * w1.y, b1i = a1r * w1.y + a1i * w1.x;
    float b2r = a2r * w2.x - a2i * w2.y, b2i = a2r * w2.y + a2i * w2.x;
    float Xr[3];
    Xr[0] = a0r + b1r + b2r;
    Xr[1] = a0r + (-0.5f * b1r - S3 * b1i) + (-0.5f * b2r + S3 * b2i);
    Xr[2] = a0r + (-0.5f * b1r + S3 * b1i) + (-0.5f * b2r - S3 * b2i);
    size_t ob = ((size_t)a * (LTOK + 1) + 1 + i) * DDIM + t;
    const float inv = 1.0f / 768.0f;
    out[ob]       = Xr[0] * inv;
    out[ob + 256] = Xr[1] * inv;
    out[ob + 512] = Xr[2] * inv;
    __syncthreads();
  }
}

// ---------------------------------------------------------------------------
extern "C" void kernel_launch(void* const* d_in, const int* in_sizes, int n_in,
                              void* d_out, int out_size, void* d_ws, size_t ws_size,
                              hipStream_t stream) {
  (void)in_sizes; (void)n_in; (void)out_size; (void)ws_size;
  const float* x    = (const float*)d_in[0];   // (2,197,768)
  const float* imgs = (const float*)d_in[1];   // (2,3,224,224)
  const float* ls   = (const float*)d_in[2];   // (2,196,196,1)
  const float* nz   = (const float*)d_in[3];   // (2,196,196,1)
  float* out = (float*)d_out;                  // (2,197,768)

  float* wf   = (float*)d_ws;
  float* uT   = wf;                       // 768 x 392; reused as savg in phase 4+
  float* sty  = wf + (size_t)NLD;
  float* phre = wf + 2 * (size_t)NLD;
  float* phim = wf + 3 * (size_t)NLD;
  float* sstd = wf + 4 * (size_t)NLD;
  float* smsk = wf + 5 * (size_t)NLD;
  float* numP = wf + 6 * (size_t)NLD;     // 4 x NLD
  float* denP = wf + 10 * (size_t)NLD;    // 4 x NLD
  u64* Mb = (u64*)(wf + 14 * (size_t)NLD);

  void* args[] = { (void*)&imgs, (void*)&x, (void*)&ls, (void*)&nz, (void*)&out,
                   (void*)&uT, (void*)&sty, (void*)&phre, (void*)&phim,
                   (void*)&sstd, (void*)&smsk, (void*)&numP, (void*)&denP,
                   (void*)&Mb };
  hipLaunchCooperativeKernel((const void*)k_mono, dim3(GRID), dim3(256),
                             args, 0, stream);
}

// Round 6
// 149.475 us; speedup vs baseline: 2.9155x; 2.9155x over previous
//
#include <hip/hip_runtime.h>
#include <math.h>

typedef unsigned long long u64;

#define NBATCH 2
#define LTOK 196
#define DDIM 768
#define NROWS (NBATCH*LTOK)      // 392
#define NLD (NBATCH*LTOK*DDIM)   // 301056

#define PI_F 3.14159265358979323846f
#define S3 0.86602540378443864676f   // sqrt(3)/2

// combine tiling: 2(a) x 28(i-tile of 7) x 3(d-chunk) x 4(j-chunk of 49) = 672 blocks
#define RT 7
#define JCH 4
#define JLEN 49

// ---------------------------------------------------------------------------
// FFT768 = 3 x FFT256 (radix-2 DIT, bit-reversed in-place) + radix-3 combine.
// ---------------------------------------------------------------------------
__device__ __forceinline__ void fft_butterfly(float* re, float* im,
                                              const float2* T,
                                              int tau, int s, int half) {
  int sub = tau >> 7;            // 0..2
  int b = tau & 127;
  int j = b & (half - 1);
  int p0 = (sub << 8) + ((b >> (s - 1)) << s) + j;
  int p1 = p0 + half;
  float2 w = T[j << (8 - s)];
  float xr = re[p1], xi = im[p1];
  float tr = w.x * xr - w.y * xi;
  float ti = w.x * xi + w.y * xr;
  float ur = re[p0], ui = im[p0];
  re[p0] = ur + tr; im[p0] = ui + ti;
  re[p1] = ur - tr; im[p1] = ui - ti;
}

__device__ __forceinline__ void fft_stages(float* re, float* im,
                                           const float2* T, int t) {
#pragma unroll
  for (int s = 1; s <= 8; s++) {
    int half = 1 << (s - 1);
    fft_butterfly(re, im, T, t, s, half);
    if (t < 128) fft_butterfly(re, im, T, t + 256, s, half);
    __syncthreads();
  }
}

// ---------------------------------------------------------------------------
// K1: patchify + standardize -> uT (768 x 392, transposed). Block 0 zeroes
//     the sim->greedy completion counter (ws is re-poisoned every launch).
// ---------------------------------------------------------------------------
__global__ __launch_bounds__(256) void k_patch(const float* __restrict__ imgs,
                                               float* __restrict__ uT,
                                               unsigned int* __restrict__ counter) {
  int blk = blockIdx.x;            // 0..391
  int a = blk / LTOK, l = blk - a * LTOK;
  int hh = l / 14, ww = l - hh * 14;
  int t = threadIdx.x;
  if (blk == 0 && t == 0) *counter = 0u;
  float loc[3];
  double s = 0.0, sq = 0.0;
#pragma unroll
  for (int e = 0; e < 3; e++) {
    int d = t + (e << 8);
    int p = d / 48, r = d - p * 48;
    int q2 = r / 3, c = r - q2 * 3;
    float val = imgs[((size_t)(a * 3 + c) * 224 + (hh * 16 + p)) * 224 + (ww * 16 + q2)];
    loc[e] = val;
    s += (double)val;
    sq += (double)val * (double)val;
  }
#pragma unroll
  for (int o = 32; o > 0; o >>= 1) { s += __shfl_down(s, o); sq += __shfl_down(sq, o); }
  __shared__ double rs[4], rq[4];
  __shared__ float sh_mu, sh_sc;
  if ((t & 63) == 0) { rs[t >> 6] = s; rq[t >> 6] = sq; }
  __syncthreads();
  if (t == 0) {
    double S = rs[0] + rs[1] + rs[2] + rs[3];
    double Q = rq[0] + rq[1] + rq[2] + rq[3];
    double mean = S / 768.0;
    double ss = Q - S * S / 768.0;
    if (ss < 1e-30) ss = 1e-30;
    sh_mu = (float)mean;
    sh_sc = (float)(1.0 / sqrt(ss));
  }
  __syncthreads();
  float mu = sh_mu, sc = sh_sc;
  int col = a * LTOK + l;
#pragma unroll
  for (int e = 0; e < 3; e++) {
    int d = t + (e << 8);
    uT[(size_t)d * NROWS + col] = (loc[e] - mu) * sc;
  }
}

// ---------------------------------------------------------------------------
// K2: blocks [0,392): Sim row i vs j>=i -> Mb; LAST sim block (device-scope
//     counter) runs the faithful sequential greedy loop in LDS.
//     blocks [392,784): forward FFT of x rows -> sty, phase.
// ---------------------------------------------------------------------------
union SimSMem {
  struct { float ui[768]; u64 mask[4]; } sim;
  struct { u64 Ml[NROWS * 4]; int red[4]; int done; } greedy;   // 12564 B
  struct { float re[768]; float im[768]; float2 t256[128]; } fft;
};

__global__ __launch_bounds__(256) void k_simfft(const float* __restrict__ uT,
                                                const float* __restrict__ x,
                                                float* __restrict__ sty,
                                                float* __restrict__ phre,
                                                float* __restrict__ phim,
                                                u64* __restrict__ Mb,
                                                unsigned int* __restrict__ counter) {
  __shared__ SimSMem sm;
  __shared__ int s_last;
  int t = threadIdx.x;

  if (blockIdx.x >= NROWS) {
    // ---------------- forward FFT branch ----------------
    int blk = blockIdx.x - NROWS;
    int a = blk / LTOK, i = blk - a * LTOK;
    if (t < 128) {
      float sn, cs;
      __sincosf(-2.0f * PI_F * (float)t / 256.0f, &sn, &cs);
      sm.fft.t256[t] = make_float2(cs, sn);
    }
    size_t row = ((size_t)a * (LTOK + 1) + 1 + i) * DDIM;
#pragma unroll
    for (int e = 0; e < 3; e++) {
      int d = t + (e << 8);
      int m = d / 3, r = d - 3 * m;          // decimate n = 3m + r
      int p = (r << 8) + (__brev((unsigned)m) >> 24);
      sm.fft.re[p] = x[row + d];
      sm.fft.im[p] = 0.f;
    }
    __syncthreads();
    fft_stages(sm.fft.re, sm.fft.im, sm.fft.t256, t);
    float a0r = sm.fft.re[t],       a0i = sm.fft.im[t];
    float a1r = sm.fft.re[256 + t], a1i = sm.fft.im[256 + t];
    float a2r = sm.fft.re[512 + t], a2i = sm.fft.im[512 + t];
    float sn, cs;
    __sincosf(-2.0f * PI_F * (float)t / 768.0f, &sn, &cs);
    float2 w1 = make_float2(cs, sn);
    float2 w2 = make_float2(cs * cs - sn * sn, 2.f * cs * sn);
    float b1r = a1r * w1.x - a1i * w1.y, b1i = a1r * w1.y + a1i * w1.x;
    float b2r = a2r * w2.x - a2i * w2.y, b2i = a2r * w2.y + a2i * w2.x;
    float Xr[3], Xi[3];
    Xr[0] = a0r + b1r + b2r;
    Xi[0] = a0i + b1i + b2i;
    Xr[1] = a0r + (-0.5f * b1r + S3 * b1i) + (-0.5f * b2r - S3 * b2i);
    Xi[1] = a0i + (-0.5f * b1i - S3 * b1r) + (-0.5f * b2i + S3 * b2r);
    Xr[2] = a0r + (-0.5f * b1r - S3 * b1i) + (-0.5f * b2r + S3 * b2i);
    Xi[2] = a0i + (-0.5f * b1i + S3 * b1r) + (-0.5f * b2i - S3 * b2r);
    size_t ob = ((size_t)a * LTOK + i) * DDIM + t;
#pragma unroll
    for (int s = 0; s < 3; s++) {
      float mag = sqrtf(Xr[s] * Xr[s] + Xi[s] * Xi[s]);
      size_t o = ob + (s << 8);
      sty[o] = mag;
      if (mag > 0.f) { phre[o] = Xr[s] / mag; phim[o] = Xi[s] / mag; }
      else           { phre[o] = 1.f;         phim[o] = 0.f;         }
    }
    return;
  }

  // ---------------- sim branch ----------------
  {
    int task = blockIdx.x;
    int a = task / LTOK, i = task - a * LTOK;
    if (t < 4) sm.sim.mask[t] = 0ull;
    int coli = a * LTOK + i;
#pragma unroll
    for (int e = 0; e < 3; e++) {
      int d = t + (e << 8);
      sm.sim.ui[d] = uT[(size_t)d * NROWS + coli];
    }
    __syncthreads();
    int j = i + t;
    if (j < LTOK) {
      const float* col = uT + (a * LTOK + j);
      float dot = 0.f;
#pragma unroll 8
      for (int d = 0; d < 768; d++) dot += sm.sim.ui[d] * col[(size_t)d * NROWS];
      if (dot > 0.3f) atomicOr(&sm.sim.mask[j >> 6], 1ull << (j & 63));
    }
    __syncthreads();
    if (t < 4) Mb[((size_t)a * LTOK + i) * 4 + t] = sm.sim.mask[t];
  }
  // release our Mb writes, count completion, detect last block
  __syncthreads();           // all waves' stores drained to L2
  if (t == 0) {
    __threadfence();         // device-scope release (L2 writeback)
    unsigned prev = atomicAdd(counter, 1u);
    s_last = (prev == NROWS - 1) ? 1 : 0;
  }
  __syncthreads();
  if (!s_last) return;

  // ---------------- greedy (last block only) ----------------
  __threadfence();           // acquire
  for (int w = t; w < NROWS * 4; w += 256)
    sm.greedy.Ml[w] = __hip_atomic_load(&Mb[w], __ATOMIC_ACQUIRE, __HIP_MEMORY_SCOPE_AGENT);
  __syncthreads();
  for (int i = 0; i < LTOK - 1; i++) {
    int s = 0;
    for (int w = t; w < NROWS * 4; w += 256) s += __popcll(sm.greedy.Ml[w]);
#pragma unroll
    for (int o = 32; o > 0; o >>= 1) s += __shfl_down(s, o);
    if ((t & 63) == 0) sm.greedy.red[t >> 6] = s;
    __syncthreads();
    if (t == 0)
      sm.greedy.done = ((sm.greedy.red[0] + sm.greedy.red[1] +
                         sm.greedy.red[2] + sm.greedy.red[3]) == NROWS) ? 1 : 0;
    __syncthreads();
    if (sm.greedy.done) break;
    for (int w = t; w < NROWS * 4; w += 256) {
      int a = w / (LTOK * 4);
      int rem = w - a * (LTOK * 4);
      int r = rem >> 2, wi = rem & 3;
      if (r > i) sm.greedy.Ml[w] &= ~sm.greedy.Ml[(a * LTOK + i) * 4 + wi];
    }
    __syncthreads();
  }
  for (int w = t; w < NROWS * 4; w += 256) Mb[w] = sm.greedy.Ml[w];
}

// ---------------------------------------------------------------------------
// K3: fused stats + combine partials. grid = 2*28*3*4 = 672 blocks.
// Per block: RT=7 i-rows, 256 d, 49 j. For each j: compute (avg,std,mask)
// on the fly from the bitmask (same fp expression order as the standalone
// stats kernel), then accumulate fp32 (num, den) partials.
// ---------------------------------------------------------------------------
__global__ __launch_bounds__(256) void k_combstats(const float* __restrict__ ls,
                                                   const float* __restrict__ nz,
                                                   const float* __restrict__ sty,
                                                   const u64* __restrict__ Mb,
                                                   float* __restrict__ numP,
                                                   float* __restrict__ denP) {
  int blk = blockIdx.x;
  int a = blk / 336;
  int rem = blk - a * 336;
  int it = rem / 12;
  int r2 = rem - it * 12;
  int dc = r2 >> 2;
  int jc = r2 & 3;
  int i0 = it * RT;
  int j0 = jc * JLEN;
  int t = threadIdx.x;
  int d = (dc << 8) + t;
  __shared__ float lsr[RT][JLEN], lnr[RT][JLEN];
  for (int idx = t; idx < RT * JLEN; idx += 256) {
    int ii = idx / JLEN, j = idx - ii * JLEN;
    size_t o = ((size_t)(a * LTOK + i0 + ii)) * LTOK + j0 + j;
    float l = ls[o];
    lsr[ii][j] = l;
    lnr[ii][j] = l * nz[o];
  }
  __syncthreads();
  float nm[RT], dn[RT];
#pragma unroll
  for (int ii = 0; ii < RT; ii++) { nm[ii] = 0.f; dn[ii] = 0.f; }
  for (int j = 0; j < JLEN; j++) {
    int jj = j0 + j;
    const u64* mp = Mb + ((size_t)a * LTOK + jj) * 4;   // uniform -> s_load
    u64 mr[4] = {mp[0], mp[1], mp[2], mp[3]};
    int num = __popcll(mr[0]) + __popcll(mr[1]) + __popcll(mr[2]) + __popcll(mr[3]);
    float fnum = fmaxf((float)num, 1e-7f);
    // pass 1: masked sum -> avg
    float acc = 0.f;
#pragma unroll
    for (int w = 0; w < 4; w++) {
      u64 m = mr[w];
      while (m) {
        int b = __ffsll(m) - 1; m &= (m - 1);
        int k = (w << 6) + b;
        acc += sty[((size_t)a * LTOK + k) * DDIM + d];
      }
    }
    float av = acc / fnum;
    // pass 2: masked squared deviation -> std
    float sq = 0.f;
#pragma unroll
    for (int w = 0; w < 4; w++) {
      u64 m = mr[w];
      while (m) {
        int b = __ffsll(m) - 1; m &= (m - 1);
        int k = (w << 6) + b;
        float dv = sty[((size_t)a * LTOK + k) * DDIM + d] - av;
        sq += dv * dv;
      }
    }
    float smv = acc > 0.f ? 1.f : 0.f;
    float msd = smv * sqrtf(sq / fnum);
    float mav = smv * av;
#pragma unroll
    for (int ii = 0; ii < RT; ii++) {
      nm[ii] += lnr[ii][j] * msd;
      nm[ii] += lsr[ii][j] * mav;
      dn[ii] += lsr[ii][j] * smv;
    }
  }
#pragma unroll
  for (int ii = 0; ii < RT; ii++) {
    size_t o = ((size_t)jc * NROWS + (a * LTOK + i0 + ii)) * DDIM + d;
    numP[o] = nm[ii];
    denP[o] = dn[ii];
  }
}

// ---------------------------------------------------------------------------
// K4: reduce 4 partials -> ssum, inverse FFT, real part, /768; cls rows.
// ---------------------------------------------------------------------------
__global__ __launch_bounds__(256) void k_ifft(const float* __restrict__ x,
                                              const float* __restrict__ numP,
                                              const float* __restrict__ denP,
                                              const float* __restrict__ phre,
                                              const float* __restrict__ phim,
                                              float* __restrict__ out) {
  int blk = blockIdx.x;
  int t = threadIdx.x;
  if (blk < NBATCH) {  // cls token rows
    size_t b = (size_t)blk * (LTOK + 1) * DDIM;
    out[b + t] = x[b + t];
    out[b + t + 256] = x[b + t + 256];
    out[b + t + 512] = x[b + t + 512];
    return;
  }
  int rr = blk - NBATCH;
  int a = rr / LTOK, i = rr - a * LTOK;
  __shared__ float re[768], im[768];
  __shared__ float2 t256[128];    // e^{+2pi i q/256}
  if (t < 128) {
    float sn, cs;
    __sincosf(2.0f * PI_F * (float)t / 256.0f, &sn, &cs);
    t256[t] = make_float2(cs, sn);
  }
  size_t rowz = ((size_t)a * LTOK + i) * DDIM;
#pragma unroll
  for (int e = 0; e < 3; e++) {
    int d = t + (e << 8);
    float num = 0.f, den = 0.f;
#pragma unroll
    for (int jc = 0; jc < JCH; jc++) {
      size_t o = (size_t)jc * NROWS * DDIM + rowz + d;
      num += numP[o];
      den += denP[o];
    }
    float mg = num / fmaxf(den, 1e-7f);
    int m = d / 3, r = d - 3 * m;          // decimate k = 3m + r
    int p = (r << 8) + (__brev((unsigned)m) >> 24);
    re[p] = mg * phre[rowz + d];
    im[p] = mg * phim[rowz + d];
  }
  __syncthreads();
  fft_stages(re, im, t256, t);
  float a0r = re[t],       a0i = im[t];
  float a1r = re[256 + t], a1i = im[256 + t];
  float a2r = re[512 + t], a2i = im[512 + t];
  float sn, cs;
  __sincosf(2.0f * PI_F * (float)t / 768.0f, &sn, &cs);
  float2 w1 = make_float2(cs, sn);
  float2 w2 = make_float2(cs * cs - sn * sn, 2.f * cs * sn);
  float b1r = a1r * w1.x - a1i * w1.y, b1i = a1r * w1.y + a1i * w1.x;
  float b2r = a2r * w2.x - a2i * w2.y, b2i = a2r * w2.y + a2i * w2.x;
  float Xr[3];
  Xr[0] = a0r + b1r + b2r;
  Xr[1] = a0r + (-0.5f * b1r - S3 * b1i) + (-0.5f * b2r + S3 * b2i);
  Xr[2] = a0r + (-0.5f * b1r + S3 * b1i) + (-0.5f * b2r - S3 * b2i);
  size_t ob = ((size_t)a * (LTOK + 1) + 1 + i) * DDIM + t;
  const float inv = 1.0f / 768.0f;
  out[ob]       = Xr[0] * inv;
  out[ob + 256] = Xr[1] * inv;
  out[ob + 512] = Xr[2] * inv;
}

// ---------------------------------------------------------------------------
extern "C" void kernel_launch(void* const* d_in, const int* in_sizes, int n_in,
                              void* d_out, int out_size, void* d_ws, size_t ws_size,
                              hipStream_t stream) {
  (void)in_sizes; (void)n_in; (void)out_size; (void)ws_size;
  const float* x    = (const float*)d_in[0];   // (2,197,768)
  const float* imgs = (const float*)d_in[1];   // (2,3,224,224)
  const float* ls   = (const float*)d_in[2];   // (2,196,196,1)
  const float* nz   = (const float*)d_in[3];   // (2,196,196,1)
  float* out = (float*)d_out;                  // (2,197,768)

  float* wf   = (float*)d_ws;
  float* uT   = wf;                       // 768 x 392
  float* sty  = wf + (size_t)NLD;
  float* phre = wf + 2 * (size_t)NLD;
  float* phim = wf + 3 * (size_t)NLD;
  float* numP = wf + 4 * (size_t)NLD;     // 4 x NLD
  float* denP = wf + 8 * (size_t)NLD;     // 4 x NLD
  u64* Mb = (u64*)(wf + 12 * (size_t)NLD);             // 1568 u64
  unsigned int* counter = (unsigned int*)(Mb + NROWS * 4);

  k_patch    <<<NROWS, 256, 0, stream>>>(imgs, uT, counter);
  k_simfft   <<<2 * NROWS, 256, 0, stream>>>(uT, x, sty, phre, phim, Mb, counter);
  k_combstats<<<NBATCH * 28 * 3 * JCH, 256, 0, stream>>>(ls, nz, sty, Mb, numP, denP);
  k_ifft     <<<NBATCH + NROWS, 256, 0, stream>>>(x, numP, denP, phre, phim, out);
}

// Round 7
// 147.806 us; speedup vs baseline: 2.9484x; 1.0113x over previous
//
#include <hip/hip_runtime.h>
#include <math.h>

typedef unsigned long long u64;

#define NBATCH 2
#define LTOK 196
#define DDIM 768
#define NROWS (NBATCH*LTOK)      // 392
#define NLD (NBATCH*LTOK*DDIM)   // 301056

#define PI_F 3.14159265358979323846f
#define S3 0.86602540378443864676f   // sqrt(3)/2

// combine tiling: 2(a) x 28(i-tile of 7) x 3(d-chunk) x 4(j-chunk of 49) = 672 blocks
#define RT 7
#define JCH 4
#define JLEN 49

// ---------------------------------------------------------------------------
// FFT768 = 3 x FFT256 (radix-2 DIT, bit-reversed in-place) + radix-3 combine.
// ---------------------------------------------------------------------------
__device__ __forceinline__ void fft_butterfly(float* re, float* im,
                                              const float2* T,
                                              int tau, int s, int half) {
  int sub = tau >> 7;            // 0..2
  int b = tau & 127;
  int j = b & (half - 1);
  int p0 = (sub << 8) + ((b >> (s - 1)) << s) + j;
  int p1 = p0 + half;
  float2 w = T[j << (8 - s)];
  float xr = re[p1], xi = im[p1];
  float tr = w.x * xr - w.y * xi;
  float ti = w.x * xi + w.y * xr;
  float ur = re[p0], ui = im[p0];
  re[p0] = ur + tr; im[p0] = ui + ti;
  re[p1] = ur - tr; im[p1] = ui - ti;
}

__device__ __forceinline__ void fft_stages(float* re, float* im,
                                           const float2* T, int t) {
#pragma unroll
  for (int s = 1; s <= 8; s++) {
    int half = 1 << (s - 1);
    fft_butterfly(re, im, T, t, s, half);
    if (t < 128) fft_butterfly(re, im, T, t + 256, s, half);
    __syncthreads();
  }
}

// ---------------------------------------------------------------------------
// K1 "pre": blocks [0,392)   patchify+standardize -> u (row-major) AND uT
//           blocks [392,784) forward FFT of x rows -> sty, phase
//           blocks [784,786) cls-token copy; block 784 zeroes the counter
// Patch load mapping: thread t <-> (p=t>>4, q=t&15), loop c=0..2 -> each wave
// reads 4 contiguous 64B segments per instr (coalesced), d = 3t + c.
// ---------------------------------------------------------------------------
__global__ __launch_bounds__(256) void k_pre(const float* __restrict__ imgs,
                                             const float* __restrict__ x,
                                             float* __restrict__ u,
                                             float* __restrict__ uT,
                                             float* __restrict__ sty,
                                             float* __restrict__ phre,
                                             float* __restrict__ phim,
                                             float* __restrict__ out,
                                             unsigned int* __restrict__ counter) {
  int t = threadIdx.x;
  if (blockIdx.x >= 2 * NROWS) {            // cls rows + counter init
    int a = blockIdx.x - 2 * NROWS;
    if (a == 0 && t == 0) *counter = 0u;
    size_t b = (size_t)a * (LTOK + 1) * DDIM;
    out[b + t] = x[b + t];
    out[b + t + 256] = x[b + t + 256];
    out[b + t + 512] = x[b + t + 512];
    return;
  }
  if (blockIdx.x < NROWS) {
    // ---- patch branch ----
    int blk = blockIdx.x;
    int a = blk / LTOK, l = blk - a * LTOK;
    int hh = l / 14, ww = l - hh * 14;
    int p = t >> 4, q = t & 15;
    float loc[3];
    double s = 0.0, sq = 0.0;
#pragma unroll
    for (int c = 0; c < 3; c++) {
      float val = imgs[((size_t)(a * 3 + c) * 224 + (hh * 16 + p)) * 224 + (ww * 16 + q)];
      loc[c] = val;
      s += (double)val;
      sq += (double)val * (double)val;
    }
#pragma unroll
    for (int o = 32; o > 0; o >>= 1) { s += __shfl_down(s, o); sq += __shfl_down(sq, o); }
    __shared__ double rs[4], rq[4];
    __shared__ float sh_mu, sh_sc;
    if ((t & 63) == 0) { rs[t >> 6] = s; rq[t >> 6] = sq; }
    __syncthreads();
    if (t == 0) {
      double S = rs[0] + rs[1] + rs[2] + rs[3];
      double Q = rq[0] + rq[1] + rq[2] + rq[3];
      double mean = S / 768.0;
      double ss = Q - S * S / 768.0;
      if (ss < 1e-30) ss = 1e-30;
      sh_mu = (float)mean;
      sh_sc = (float)(1.0 / sqrt(ss));
    }
    __syncthreads();
    float mu = sh_mu, sc = sh_sc;
    int col = a * LTOK + l;
    size_t rbase = (size_t)col * DDIM;
#pragma unroll
    for (int c = 0; c < 3; c++) {
      int d = 3 * t + c;
      float v = (loc[c] - mu) * sc;
      u[rbase + d] = v;
      uT[(size_t)d * NROWS + col] = v;
    }
  } else {
    // ---- forward FFT branch ----
    int blk = blockIdx.x - NROWS;
    int a = blk / LTOK, i = blk - a * LTOK;
    __shared__ float re[768], im[768];
    __shared__ float2 t256[128];    // e^{-2pi i q/256}
    if (t < 128) {
      float sn, cs;
      __sincosf(-2.0f * PI_F * (float)t / 256.0f, &sn, &cs);
      t256[t] = make_float2(cs, sn);
    }
    size_t row = ((size_t)a * (LTOK + 1) + 1 + i) * DDIM;
#pragma unroll
    for (int e = 0; e < 3; e++) {
      int d = t + (e << 8);
      int m = d / 3, r = d - 3 * m;          // decimate n = 3m + r
      int p = (r << 8) + (__brev((unsigned)m) >> 24);
      re[p] = x[row + d];
      im[p] = 0.f;
    }
    __syncthreads();
    fft_stages(re, im, t256, t);
    float a0r = re[t],       a0i = im[t];
    float a1r = re[256 + t], a1i = im[256 + t];
    float a2r = re[512 + t], a2i = im[512 + t];
    float sn, cs;
    __sincosf(-2.0f * PI_F * (float)t / 768.0f, &sn, &cs);
    float2 w1 = make_float2(cs, sn);
    float2 w2 = make_float2(cs * cs - sn * sn, 2.f * cs * sn);
    float b1r = a1r * w1.x - a1i * w1.y, b1i = a1r * w1.y + a1i * w1.x;
    float b2r = a2r * w2.x - a2i * w2.y, b2i = a2r * w2.y + a2i * w2.x;
    float Xr[3], Xi[3];
    Xr[0] = a0r + b1r + b2r;
    Xi[0] = a0i + b1i + b2i;
    Xr[1] = a0r + (-0.5f * b1r + S3 * b1i) + (-0.5f * b2r - S3 * b2i);
    Xi[1] = a0i + (-0.5f * b1i - S3 * b1r) + (-0.5f * b2i + S3 * b2r);
    Xr[2] = a0r + (-0.5f * b1r - S3 * b1i) + (-0.5f * b2r + S3 * b2i);
    Xi[2] = a0i + (-0.5f * b1i + S3 * b1r) + (-0.5f * b2i - S3 * b2r);
    size_t ob = ((size_t)a * LTOK + i) * DDIM + t;
#pragma unroll
    for (int s = 0; s < 3; s++) {
      float mag = sqrtf(Xr[s] * Xr[s] + Xi[s] * Xi[s]);
      size_t o = ob + (s << 8);
      sty[o] = mag;
      if (mag > 0.f) { phre[o] = Xr[s] / mag; phim[o] = Xi[s] / mag; }
      else           { phre[o] = 1.f;         phim[o] = 0.f;         }
    }
  }
}

// ---------------------------------------------------------------------------
// K2: Sim row i vs j>=i (ui broadcast from row-major u = coalesced; dot loop
//     over transposed uT columns = coalesced). Last block runs the faithful
//     sequential greedy loop in LDS (device-scope counter handoff).
// ---------------------------------------------------------------------------
union SimSMem {
  struct { float ui[768]; u64 mask[4]; } sim;
  struct { u64 Ml[NROWS * 4]; int red[4]; int done; } greedy;   // 12564 B
};

__global__ __launch_bounds__(256) void k_sim(const float* __restrict__ u,
                                             const float* __restrict__ uT,
                                             u64* __restrict__ Mb,
                                             unsigned int* __restrict__ counter) {
  __shared__ SimSMem sm;
  __shared__ int s_last;
  int t = threadIdx.x;
  {
    int task = blockIdx.x;
    int a = task / LTOK, i = task - a * LTOK;
    if (t < 4) sm.sim.mask[t] = 0ull;
    size_t rbase = ((size_t)a * LTOK + i) * DDIM;
#pragma unroll
    for (int e = 0; e < 3; e++) {
      int d = t + (e << 8);
      sm.sim.ui[d] = u[rbase + d];
    }
    __syncthreads();
    int j = i + t;
    if (j < LTOK) {
      const float* col = uT + (a * LTOK + j);
      float dot = 0.f;
#pragma unroll 8
      for (int d = 0; d < 768; d++) dot += sm.sim.ui[d] * col[(size_t)d * NROWS];
      if (dot > 0.3f) atomicOr(&sm.sim.mask[j >> 6], 1ull << (j & 63));
    }
    __syncthreads();
    if (t < 4) Mb[((size_t)a * LTOK + i) * 4 + t] = sm.sim.mask[t];
  }
  __syncthreads();
  if (t == 0) {
    __threadfence();         // device-scope release of our Mb row
    unsigned prev = atomicAdd(counter, 1u);
    s_last = (prev == NROWS - 1) ? 1 : 0;
  }
  __syncthreads();
  if (!s_last) return;

  // ---------------- greedy (last block only) ----------------
  __threadfence();           // acquire
  for (int w = t; w < NROWS * 4; w += 256)
    sm.greedy.Ml[w] = __hip_atomic_load(&Mb[w], __ATOMIC_ACQUIRE, __HIP_MEMORY_SCOPE_AGENT);
  __syncthreads();
  for (int i = 0; i < LTOK - 1; i++) {
    int s = 0;
    for (int w = t; w < NROWS * 4; w += 256) s += __popcll(sm.greedy.Ml[w]);
#pragma unroll
    for (int o = 32; o > 0; o >>= 1) s += __shfl_down(s, o);
    if ((t & 63) == 0) sm.greedy.red[t >> 6] = s;
    __syncthreads();
    if (t == 0)
      sm.greedy.done = ((sm.greedy.red[0] + sm.greedy.red[1] +
                         sm.greedy.red[2] + sm.greedy.red[3]) == NROWS) ? 1 : 0;
    __syncthreads();
    if (sm.greedy.done) break;
    for (int w = t; w < NROWS * 4; w += 256) {
      int a = w / (LTOK * 4);
      int rem = w - a * (LTOK * 4);
      int r = rem >> 2, wi = rem & 3;
      if (r > i) sm.greedy.Ml[w] &= ~sm.greedy.Ml[(a * LTOK + i) * 4 + wi];
    }
    __syncthreads();
  }
  for (int w = t; w < NROWS * 4; w += 256) Mb[w] = sm.greedy.Ml[w];
}

// ---------------------------------------------------------------------------
// K3: masked stats per row — gather coalesced across threads (sr[t]); serial
//     chain only over mask bits. Writes mask, mask*avg, mask*std.
// ---------------------------------------------------------------------------
__global__ __launch_bounds__(256) void k_stats(const u64* __restrict__ Mb,
                                               const float* __restrict__ sty,
                                               float* __restrict__ savg,
                                               float* __restrict__ sstd,
                                               float* __restrict__ smsk) {
  int blk = blockIdx.x;
  int a = blk / LTOK, i = blk - a * LTOK;
  __shared__ u64 mrow[4];
  int t = threadIdx.x;
  if (t < 4) mrow[t] = Mb[((size_t)a * LTOK + i) * 4 + t];
  __syncthreads();
  int num = __popcll(mrow[0]) + __popcll(mrow[1]) + __popcll(mrow[2]) + __popcll(mrow[3]);
  float fnum = fmaxf((float)num, 1e-7f);
  float acc0 = 0.f, acc1 = 0.f, acc2 = 0.f;
  for (int w = 0; w < 4; w++) {
    u64 m = mrow[w];
    while (m) {
      int b = __ffsll(m) - 1; m &= (m - 1);
      int j = (w << 6) + b;
      const float* sr = sty + ((size_t)a * LTOK + j) * DDIM;
      acc0 += sr[t]; acc1 += sr[t + 256]; acc2 += sr[t + 512];
    }
  }
  float av0 = acc0 / fnum, av1 = acc1 / fnum, av2 = acc2 / fnum;
  float sq0 = 0.f, sq1 = 0.f, sq2 = 0.f;
  for (int w = 0; w < 4; w++) {
    u64 m = mrow[w];
    while (m) {
      int b = __ffsll(m) - 1; m &= (m - 1);
      int j = (w << 6) + b;
      const float* sr = sty + ((size_t)a * LTOK + j) * DDIM;
      float d0 = sr[t] - av0, d1 = sr[t + 256] - av1, d2 = sr[t + 512] - av2;
      sq0 += d0 * d0; sq1 += d1 * d1; sq2 += d2 * d2;
    }
  }
  size_t o = ((size_t)a * LTOK + i) * DDIM + t;
  float mk0 = acc0 > 0.f ? 1.f : 0.f;
  float mk1 = acc1 > 0.f ? 1.f : 0.f;
  float mk2 = acc2 > 0.f ? 1.f : 0.f;
  smsk[o] = mk0;            smsk[o + 256] = mk1;            smsk[o + 512] = mk2;
  savg[o] = mk0 * av0;      savg[o + 256] = mk1 * av1;      savg[o + 512] = mk2 * av2;
  sstd[o] = mk0 * sqrtf(sq0 / fnum);
  sstd[o + 256] = mk1 * sqrtf(sq1 / fnum);
  sstd[o + 512] = mk2 * sqrtf(sq2 / fnum);
}

// ---------------------------------------------------------------------------
// K4: combine partials. grid = 2*28*3*4 = 672 blocks; streams precomputed
//     stats coalesced; writes fp32 (num, den) partials per j-chunk.
// ---------------------------------------------------------------------------
__global__ __launch_bounds__(256) void k_comb(const float* __restrict__ ls,
                                              const float* __restrict__ nz,
                                              const float* __restrict__ savg,
                                              const float* __restrict__ sstd,
                                              const float* __restrict__ smsk,
                                              float* __restrict__ numP,
                                              float* __restrict__ denP) {
  int blk = blockIdx.x;
  int a = blk / 336;
  int rem = blk - a * 336;
  int it = rem / 12;
  int r2 = rem - it * 12;
  int dc = r2 >> 2;
  int jc = r2 & 3;
  int i0 = it * RT;
  int j0 = jc * JLEN;
  int t = threadIdx.x;
  int d = (dc << 8) + t;
  __shared__ float lsr[RT][JLEN], lnr[RT][JLEN];
  for (int idx = t; idx < RT * JLEN; idx += 256) {
    int ii = idx / JLEN, j = idx - ii * JLEN;
    size_t o = ((size_t)(a * LTOK + i0 + ii)) * LTOK + j0 + j;
    float l = ls[o];
    lsr[ii][j] = l;
    lnr[ii][j] = l * nz[o];
  }
  __syncthreads();
  float nm[RT], dn[RT];
#pragma unroll
  for (int ii = 0; ii < RT; ii++) { nm[ii] = 0.f; dn[ii] = 0.f; }
#pragma unroll 7
  for (int j = 0; j < JLEN; j++) {
    size_t b = ((size_t)(a * LTOK + j0 + j)) * DDIM + d;
    float sd = sstd[b], sv = savg[b], sm = smsk[b];
#pragma unroll
    for (int ii = 0; ii < RT; ii++) {
      nm[ii] += lnr[ii][j] * sd;
      nm[ii] += lsr[ii][j] * sv;
      dn[ii] += lsr[ii][j] * sm;
    }
  }
#pragma unroll
  for (int ii = 0; ii < RT; ii++) {
    size_t o = ((size_t)jc * NROWS + (a * LTOK + i0 + ii)) * DDIM + d;
    numP[o] = nm[ii];
    denP[o] = dn[ii];
  }
}

// ---------------------------------------------------------------------------
// K5: reduce 4 partials -> ssum, inverse FFT, real part, /768.
// ---------------------------------------------------------------------------
__global__ __launch_bounds__(256) void k_ifft(const float* __restrict__ numP,
                                              const float* __restrict__ denP,
                                              const float* __restrict__ phre,
                                              const float* __restrict__ phim,
                                              float* __restrict__ out) {
  int rr = blockIdx.x;
  int t = threadIdx.x;
  int a = rr / LTOK, i = rr - a * LTOK;
  __shared__ float re[768], im[768];
  __shared__ float2 t256[128];    // e^{+2pi i q/256}
  if (t < 128) {
    float sn, cs;
    __sincosf(2.0f * PI_F * (float)t / 256.0f, &sn, &cs);
    t256[t] = make_float2(cs, sn);
  }
  size_t rowz = ((size_t)a * LTOK + i) * DDIM;
#pragma unroll
  for (int e = 0; e < 3; e++) {
    int d = t + (e << 8);
    float num = 0.f, den = 0.f;
#pragma unroll
    for (int jc = 0; jc < JCH; jc++) {
      size_t o = (size_t)jc * NROWS * DDIM + rowz + d;
      num += numP[o];
      den += denP[o];
    }
    float mg = num / fmaxf(den, 1e-7f);
    int m = d / 3, r = d - 3 * m;          // decimate k = 3m + r
    int p = (r << 8) + (__brev((unsigned)m) >> 24);
    re[p] = mg * phre[rowz + d];
    im[p] = mg * phim[rowz + d];
  }
  __syncthreads();
  fft_stages(re, im, t256, t);
  float a0r = re[t],       a0i = im[t];
  float a1r = re[256 + t], a1i = im[256 + t];
  float a2r = re[512 + t], a2i = im[512 + t];
  float sn, cs;
  __sincosf(2.0f * PI_F * (float)t / 768.0f, &sn, &cs);
  float2 w1 = make_float2(cs, sn);
  float2 w2 = make_float2(cs * cs - sn * sn, 2.f * cs * sn);
  float b1r = a1r * w1.x - a1i * w1.y, b1i = a1r * w1.y + a1i * w1.x;
  float b2r = a2r * w2.x - a2i * w2.y, b2i = a2r * w2.y + a2i * w2.x;
  float Xr[3];
  Xr[0] = a0r + b1r + b2r;
  Xr[1] = a0r + (-0.5f * b1r - S3 * b1i) + (-0.5f * b2r + S3 * b2i);
  Xr[2] = a0r + (-0.5f * b1r + S3 * b1i) + (-0.5f * b2r - S3 * b2i);
  size_t ob = ((size_t)a * (LTOK + 1) + 1 + i) * DDIM + t;
  const float inv = 1.0f / 768.0f;
  out[ob]       = Xr[0] * inv;
  out[ob + 256] = Xr[1] * inv;
  out[ob + 512] = Xr[2] * inv;
}

// ---------------------------------------------------------------------------
extern "C" void kernel_launch(void* const* d_in, const int* in_sizes, int n_in,
                              void* d_out, int out_size, void* d_ws, size_t ws_size,
                              hipStream_t stream) {
  (void)in_sizes; (void)n_in; (void)out_size; (void)ws_size;
  const float* x    = (const float*)d_in[0];   // (2,197,768)
  const float* imgs = (const float*)d_in[1];   // (2,3,224,224)
  const float* ls   = (const float*)d_in[2];   // (2,196,196,1)
  const float* nz   = (const float*)d_in[3];   // (2,196,196,1)
  float* out = (float*)d_out;                  // (2,197,768)

  float* wf   = (float*)d_ws;
  float* u    = wf;                        // row-major 392 x 768
  float* uT   = wf + (size_t)NLD;          // transposed 768 x 392
  float* sty  = wf + 2 * (size_t)NLD;
  float* phre = wf + 3 * (size_t)NLD;
  float* phim = wf + 4 * (size_t)NLD;
  float* savg = wf + 5 * (size_t)NLD;
  float* sstd = wf + 6 * (size_t)NLD;
  float* smsk = wf + 7 * (size_t)NLD;
  float* numP = wf + 8 * (size_t)NLD;      // 4 x NLD
  float* denP = wf + 12 * (size_t)NLD;     // 4 x NLD
  u64* Mb = (u64*)(wf + 16 * (size_t)NLD); // 1568 u64
  unsigned int* counter = (unsigned int*)(Mb + NROWS * 4);

  k_pre  <<<2 * NROWS + NBATCH, 256, 0, stream>>>(imgs, x, u, uT, sty, phre, phim, out, counter);
  k_sim  <<<NROWS, 256, 0, stream>>>(u, uT, Mb, counter);
  k_stats<<<NROWS, 256, 0, stream>>>(Mb, sty, savg, sstd, smsk);
  k_comb <<<NBATCH * 28 * 3 * JCH, 256, 0, stream>>>(ls, nz, savg, sstd, smsk, numP, denP);
  k_ifft <<<NROWS, 256, 0, stream>>>(numP, denP, phre, phim, out);
}

// Round 8
// 137.869 us; speedup vs baseline: 3.1609x; 1.0721x over previous
//
#include <hip/hip_runtime.h>
#include <math.h>

typedef unsigned long long u64;

#define NBATCH 2
#define LTOK 196
#define DDIM 768
#define NROWS (NBATCH*LTOK)      // 392
#define NLD (NBATCH*LTOK*DDIM)   // 301056

#define PI_F 3.14159265358979323846f
#define S3 0.86602540378443864676f   // sqrt(3)/2

// combine tiling: 2(a) x 28(i-tile of 7) x 3(d-chunk) x 4(j-chunk of 49) = 672 blocks
#define RT 7
#define JCH 4
#define JLEN 49

// sim tiling: 7 i-tiles of 32; upper-triangle pairs = 28; x2 batches = 56 blocks
#define NSIMBLK (2 * 28)

// ---------------------------------------------------------------------------
// FFT768 = 3 x FFT256 (radix-2 DIT, bit-reversed in-place) + radix-3 combine.
// ---------------------------------------------------------------------------
__device__ __forceinline__ void fft_butterfly(float* re, float* im,
                                              const float2* T,
                                              int tau, int s, int half) {
  int sub = tau >> 7;            // 0..2
  int b = tau & 127;
  int j = b & (half - 1);
  int p0 = (sub << 8) + ((b >> (s - 1)) << s) + j;
  int p1 = p0 + half;
  float2 w = T[j << (8 - s)];
  float xr = re[p1], xi = im[p1];
  float tr = w.x * xr - w.y * xi;
  float ti = w.x * xi + w.y * xr;
  float ur = re[p0], ui = im[p0];
  re[p0] = ur + tr; im[p0] = ui + ti;
  re[p1] = ur - tr; im[p1] = ui - ti;
}

__device__ __forceinline__ void fft_stages(float* re, float* im,
                                           const float2* T, int t) {
#pragma unroll
  for (int s = 1; s <= 8; s++) {
    int half = 1 << (s - 1);
    fft_butterfly(re, im, T, t, s, half);
    if (t < 128) fft_butterfly(re, im, T, t + 256, s, half);
    __syncthreads();
  }
}

// ---------------------------------------------------------------------------
// K1 "pre": blocks [0,392)   patchify+standardize -> u (row-major)
//           blocks [392,784) forward FFT of x rows -> sty, phase
//           blocks [784,786) cls-token copy; block 784 zeroes counter + Mb
// ---------------------------------------------------------------------------
__global__ __launch_bounds__(256) void k_pre(const float* __restrict__ imgs,
                                             const float* __restrict__ x,
                                             float* __restrict__ u,
                                             float* __restrict__ sty,
                                             float* __restrict__ phre,
                                             float* __restrict__ phim,
                                             float* __restrict__ out,
                                             u64* __restrict__ Mb,
                                             unsigned int* __restrict__ counter) {
  int t = threadIdx.x;
  if (blockIdx.x >= 2 * NROWS) {            // cls rows + zero Mb/counter
    int a = blockIdx.x - 2 * NROWS;
    if (a == 0) {
      if (t == 0) *counter = 0u;
      for (int w = t; w < NROWS * 4; w += 256) Mb[w] = 0ull;
    }
    size_t b = (size_t)a * (LTOK + 1) * DDIM;
    out[b + t] = x[b + t];
    out[b + t + 256] = x[b + t + 256];
    out[b + t + 512] = x[b + t + 512];
    return;
  }
  if (blockIdx.x < NROWS) {
    // ---- patch branch ----
    int blk = blockIdx.x;
    int a = blk / LTOK, l = blk - a * LTOK;
    int hh = l / 14, ww = l - hh * 14;
    int p = t >> 4, q = t & 15;
    float loc[3];
    double s = 0.0, sq = 0.0;
#pragma unroll
    for (int c = 0; c < 3; c++) {
      float val = imgs[((size_t)(a * 3 + c) * 224 + (hh * 16 + p)) * 224 + (ww * 16 + q)];
      loc[c] = val;
      s += (double)val;
      sq += (double)val * (double)val;
    }
#pragma unroll
    for (int o = 32; o > 0; o >>= 1) { s += __shfl_down(s, o); sq += __shfl_down(sq, o); }
    __shared__ double rs[4], rq[4];
    __shared__ float sh_mu, sh_sc;
    if ((t & 63) == 0) { rs[t >> 6] = s; rq[t >> 6] = sq; }
    __syncthreads();
    if (t == 0) {
      double S = rs[0] + rs[1] + rs[2] + rs[3];
      double Q = rq[0] + rq[1] + rq[2] + rq[3];
      double mean = S / 768.0;
      double ss = Q - S * S / 768.0;
      if (ss < 1e-30) ss = 1e-30;
      sh_mu = (float)mean;
      sh_sc = (float)(1.0 / sqrt(ss));
    }
    __syncthreads();
    float mu = sh_mu, sc = sh_sc;
    size_t rbase = ((size_t)(a * LTOK + l)) * DDIM;
#pragma unroll
    for (int c = 0; c < 3; c++) {
      int d = 3 * t + c;
      u[rbase + d] = (loc[c] - mu) * sc;
    }
  } else {
    // ---- forward FFT branch ----
    int blk = blockIdx.x - NROWS;
    int a = blk / LTOK, i = blk - a * LTOK;
    __shared__ float re[768], im[768];
    __shared__ float2 t256[128];    // e^{-2pi i q/256}
    if (t < 128) {
      float sn, cs;
      __sincosf(-2.0f * PI_F * (float)t / 256.0f, &sn, &cs);
      t256[t] = make_float2(cs, sn);
    }
    size_t row = ((size_t)a * (LTOK + 1) + 1 + i) * DDIM;
#pragma unroll
    for (int e = 0; e < 3; e++) {
      int d = t + (e << 8);
      int m = d / 3, r = d - 3 * m;          // decimate n = 3m + r
      int p = (r << 8) + (__brev((unsigned)m) >> 24);
      re[p] = x[row + d];
      im[p] = 0.f;
    }
    __syncthreads();
    fft_stages(re, im, t256, t);
    float a0r = re[t],       a0i = im[t];
    float a1r = re[256 + t], a1i = im[256 + t];
    float a2r = re[512 + t], a2i = im[512 + t];
    float sn, cs;
    __sincosf(-2.0f * PI_F * (float)t / 768.0f, &sn, &cs);
    float2 w1 = make_float2(cs, sn);
    float2 w2 = make_float2(cs * cs - sn * sn, 2.f * cs * sn);
    float b1r = a1r * w1.x - a1i * w1.y, b1i = a1r * w1.y + a1i * w1.x;
    float b2r = a2r * w2.x - a2i * w2.y, b2i = a2r * w2.y + a2i * w2.x;
    float Xr[3], Xi[3];
    Xr[0] = a0r + b1r + b2r;
    Xi[0] = a0i + b1i + b2i;
    Xr[1] = a0r + (-0.5f * b1r + S3 * b1i) + (-0.5f * b2r - S3 * b2i);
    Xi[1] = a0i + (-0.5f * b1i - S3 * b1r) + (-0.5f * b2i + S3 * b2r);
    Xr[2] = a0r + (-0.5f * b1r - S3 * b1i) + (-0.5f * b2r + S3 * b2i);
    Xi[2] = a0i + (-0.5f * b1i + S3 * b1r) + (-0.5f * b2i - S3 * b2r);
    size_t ob = ((size_t)a * LTOK + i) * DDIM + t;
#pragma unroll
    for (int s = 0; s < 3; s++) {
      float mag = sqrtf(Xr[s] * Xr[s] + Xi[s] * Xi[s]);
      size_t o = ob + (s << 8);
      sty[o] = mag;
      if (mag > 0.f) { phre[o] = Xr[s] / mag; phim[o] = Xi[s] / mag; }
      else           { phre[o] = 1.f;         phim[o] = 0.f;         }
    }
  }
}

// ---------------------------------------------------------------------------
// K2: tiled-GEMM Sim. 56 blocks: (a, upper-tri 32x32 tile pair). Each thread
// accumulates a 2x2 register tile over K=768 staged in k-major LDS (padded).
// Bits (Sim>0.3, j>=i) atomicOr'd into zeroed Mb. Last block (device counter)
// runs the faithful sequential greedy loop in LDS.
// ---------------------------------------------------------------------------
union SimSMem {
  struct { float As[32][34]; float Bs[32][34]; } gemm;          // 8704 B
  struct { u64 Ml[NROWS * 4]; int red[4]; int done; } greedy;   // 12564 B
};

__global__ __launch_bounds__(256) void k_sim(const float* __restrict__ u,
                                             u64* __restrict__ Mb,
                                             unsigned int* __restrict__ counter) {
  __shared__ SimSMem sm;
  __shared__ int s_last;
  int t = threadIdx.x;
  {
    int a = blockIdx.x / 28;
    int p = blockIdx.x - a * 28;
    int it = 0;
    while (p >= 7 - it) { p -= 7 - it; it++; }
    int jt = it + p;
    int i0 = it << 5, j0 = jt << 5;
    int ty = t >> 4, tx = t & 15;
    int r = t >> 3;                 // 0..31
    int kq = (t & 7) << 2;          // 0,4,...,28
    float c00 = 0.f, c01 = 0.f, c10 = 0.f, c11 = 0.f;
    for (int k0 = 0; k0 < DDIM; k0 += 32) {
      {
        int row = i0 + r;
        float4 v = make_float4(0.f, 0.f, 0.f, 0.f);
        if (row < LTOK) v = *(const float4*)(u + ((size_t)(a * LTOK + row)) * DDIM + k0 + kq);
        sm.gemm.As[kq + 0][r] = v.x; sm.gemm.As[kq + 1][r] = v.y;
        sm.gemm.As[kq + 2][r] = v.z; sm.gemm.As[kq + 3][r] = v.w;
      }
      {
        int row = j0 + r;
        float4 v = make_float4(0.f, 0.f, 0.f, 0.f);
        if (row < LTOK) v = *(const float4*)(u + ((size_t)(a * LTOK + row)) * DDIM + k0 + kq);
        sm.gemm.Bs[kq + 0][r] = v.x; sm.gemm.Bs[kq + 1][r] = v.y;
        sm.gemm.Bs[kq + 2][r] = v.z; sm.gemm.Bs[kq + 3][r] = v.w;
      }
      __syncthreads();
#pragma unroll
      for (int k = 0; k < 32; k++) {
        float2 av = *(const float2*)&sm.gemm.As[k][ty << 1];
        float2 bv = *(const float2*)&sm.gemm.Bs[k][tx << 1];
        c00 += av.x * bv.x; c01 += av.x * bv.y;
        c10 += av.y * bv.x; c11 += av.y * bv.y;
      }
      __syncthreads();
    }
    float cc[2][2] = {{c00, c01}, {c10, c11}};
#pragma unroll
    for (int ii = 0; ii < 2; ii++) {
#pragma unroll
      for (int jj = 0; jj < 2; jj++) {
        int i = i0 + (ty << 1) + ii;
        int j = j0 + (tx << 1) + jj;
        if (i < LTOK && j < LTOK && j >= i && cc[ii][jj] > 0.3f)
          atomicOr(&Mb[((size_t)(a * LTOK + i)) * 4 + (j >> 6)], 1ull << (j & 63));
      }
    }
  }
  __syncthreads();
  if (t == 0) {
    __threadfence();         // device-scope release of our Mb bits
    unsigned prev = atomicAdd(counter, 1u);
    s_last = (prev == NSIMBLK - 1) ? 1 : 0;
  }
  __syncthreads();
  if (!s_last) return;

  // ---------------- greedy (last block only) ----------------
  __threadfence();           // acquire
  for (int w = t; w < NROWS * 4; w += 256)
    sm.greedy.Ml[w] = __hip_atomic_load(&Mb[w], __ATOMIC_ACQUIRE, __HIP_MEMORY_SCOPE_AGENT);
  __syncthreads();
  for (int i = 0; i < LTOK - 1; i++) {
    int s = 0;
    for (int w = t; w < NROWS * 4; w += 256) s += __popcll(sm.greedy.Ml[w]);
#pragma unroll
    for (int o = 32; o > 0; o >>= 1) s += __shfl_down(s, o);
    if ((t & 63) == 0) sm.greedy.red[t >> 6] = s;
    __syncthreads();
    if (t == 0)
      sm.greedy.done = ((sm.greedy.red[0] + sm.greedy.red[1] +
                         sm.greedy.red[2] + sm.greedy.red[3]) == NROWS) ? 1 : 0;
    __syncthreads();
    if (sm.greedy.done) break;
    for (int w = t; w < NROWS * 4; w += 256) {
      int a = w / (LTOK * 4);
      int rem = w - a * (LTOK * 4);
      int r = rem >> 2, wi = rem & 3;
      if (r > i) sm.greedy.Ml[w] &= ~sm.greedy.Ml[(a * LTOK + i) * 4 + wi];
    }
    __syncthreads();
  }
  for (int w = t; w < NROWS * 4; w += 256) Mb[w] = sm.greedy.Ml[w];
}

// ---------------------------------------------------------------------------
// K3: masked stats per row — gather coalesced across threads (sr[t]); serial
//     chain only over mask bits. Writes mask, mask*avg, mask*std.
// ---------------------------------------------------------------------------
__global__ __launch_bounds__(256) void k_stats(const u64* __restrict__ Mb,
                                               const float* __restrict__ sty,
                                               float* __restrict__ savg,
                                               float* __restrict__ sstd,
                                               float* __restrict__ smsk) {
  int blk = blockIdx.x;
  int a = blk / LTOK, i = blk - a * LTOK;
  __shared__ u64 mrow[4];
  int t = threadIdx.x;
  if (t < 4) mrow[t] = Mb[((size_t)a * LTOK + i) * 4 + t];
  __syncthreads();
  int num = __popcll(mrow[0]) + __popcll(mrow[1]) + __popcll(mrow[2]) + __popcll(mrow[3]);
  float fnum = fmaxf((float)num, 1e-7f);
  float acc0 = 0.f, acc1 = 0.f, acc2 = 0.f;
  for (int w = 0; w < 4; w++) {
    u64 m = mrow[w];
    while (m) {
      int b = __ffsll(m) - 1; m &= (m - 1);
      int j = (w << 6) + b;
      const float* sr = sty + ((size_t)a * LTOK + j) * DDIM;
      acc0 += sr[t]; acc1 += sr[t + 256]; acc2 += sr[t + 512];
    }
  }
  float av0 = acc0 / fnum, av1 = acc1 / fnum, av2 = acc2 / fnum;
  float sq0 = 0.f, sq1 = 0.f, sq2 = 0.f;
  for (int w = 0; w < 4; w++) {
    u64 m = mrow[w];
    while (m) {
      int b = __ffsll(m) - 1; m &= (m - 1);
      int j = (w << 6) + b;
      const float* sr = sty + ((size_t)a * LTOK + j) * DDIM;
      float d0 = sr[t] - av0, d1 = sr[t + 256] - av1, d2 = sr[t + 512] - av2;
      sq0 += d0 * d0; sq1 += d1 * d1; sq2 += d2 * d2;
    }
  }
  size_t o = ((size_t)a * LTOK + i) * DDIM + t;
  float mk0 = acc0 > 0.f ? 1.f : 0.f;
  float mk1 = acc1 > 0.f ? 1.f : 0.f;
  float mk2 = acc2 > 0.f ? 1.f : 0.f;
  smsk[o] = mk0;            smsk[o + 256] = mk1;            smsk[o + 512] = mk2;
  savg[o] = mk0 * av0;      savg[o + 256] = mk1 * av1;      savg[o + 512] = mk2 * av2;
  sstd[o] = mk0 * sqrtf(sq0 / fnum);
  sstd[o + 256] = mk1 * sqrtf(sq1 / fnum);
  sstd[o + 512] = mk2 * sqrtf(sq2 / fnum);
}

// ---------------------------------------------------------------------------
// K4: combine partials. grid = 2*28*3*4 = 672 blocks; streams precomputed
//     stats coalesced; writes fp32 (num, den) partials per j-chunk.
// ---------------------------------------------------------------------------
__global__ __launch_bounds__(256) void k_comb(const float* __restrict__ ls,
                                              const float* __restrict__ nz,
                                              const float* __restrict__ savg,
                                              const float* __restrict__ sstd,
                                              const float* __restrict__ smsk,
                                              float* __restrict__ numP,
                                              float* __restrict__ denP) {
  int blk = blockIdx.x;
  int a = blk / 336;
  int rem = blk - a * 336;
  int it = rem / 12;
  int r2 = rem - it * 12;
  int dc = r2 >> 2;
  int jc = r2 & 3;
  int i0 = it * RT;
  int j0 = jc * JLEN;
  int t = threadIdx.x;
  int d = (dc << 8) + t;
  __shared__ float lsr[RT][JLEN], lnr[RT][JLEN];
  for (int idx = t; idx < RT * JLEN; idx += 256) {
    int ii = idx / JLEN, j = idx - ii * JLEN;
    size_t o = ((size_t)(a * LTOK + i0 + ii)) * LTOK + j0 + j;
    float l = ls[o];
    lsr[ii][j] = l;
    lnr[ii][j] = l * nz[o];
  }
  __syncthreads();
  float nm[RT], dn[RT];
#pragma unroll
  for (int ii = 0; ii < RT; ii++) { nm[ii] = 0.f; dn[ii] = 0.f; }
#pragma unroll 7
  for (int j = 0; j < JLEN; j++) {
    size_t b = ((size_t)(a * LTOK + j0 + j)) * DDIM + d;
    float sd = sstd[b], sv = savg[b], sm = smsk[b];
#pragma unroll
    for (int ii = 0; ii < RT; ii++) {
      nm[ii] += lnr[ii][j] * sd;
      nm[ii] += lsr[ii][j] * sv;
      dn[ii] += lsr[ii][j] * sm;
    }
  }
#pragma unroll
  for (int ii = 0; ii < RT; ii++) {
    size_t o = ((size_t)jc * NROWS + (a * LTOK + i0 + ii)) * DDIM + d;
    numP[o] = nm[ii];
    denP[o] = dn[ii];
  }
}

// ---------------------------------------------------------------------------
// K5: reduce 4 partials -> ssum, inverse FFT, real part, /768.
// ---------------------------------------------------------------------------
__global__ __launch_bounds__(256) void k_ifft(const float* __restrict__ numP,
                                              const float* __restrict__ denP,
                                              const float* __restrict__ phre,
                                              const float* __restrict__ phim,
                                              float* __restrict__ out) {
  int rr = blockIdx.x;
  int t = threadIdx.x;
  int a = rr / LTOK, i = rr - a * LTOK;
  __shared__ float re[768], im[768];
  __shared__ float2 t256[128];    // e^{+2pi i q/256}
  if (t < 128) {
    float sn, cs;
    __sincosf(2.0f * PI_F * (float)t / 256.0f, &sn, &cs);
    t256[t] = make_float2(cs, sn);
  }
  size_t rowz = ((size_t)a * LTOK + i) * DDIM;
#pragma unroll
  for (int e = 0; e < 3; e++) {
    int d = t + (e << 8);
    float num = 0.f, den = 0.f;
#pragma unroll
    for (int jc = 0; jc < JCH; jc++) {
      size_t o = (size_t)jc * NROWS * DDIM + rowz + d;
      num += numP[o];
      den += denP[o];
    }
    float mg = num / fmaxf(den, 1e-7f);
    int m = d / 3, r = d - 3 * m;          // decimate k = 3m + r
    int p = (r << 8) + (__brev((unsigned)m) >> 24);
    re[p] = mg * phre[rowz + d];
    im[p] = mg * phim[rowz + d];
  }
  __syncthreads();
  fft_stages(re, im, t256, t);
  float a0r = re[t],       a0i = im[t];
  float a1r = re[256 + t], a1i = im[256 + t];
  float a2r = re[512 + t], a2i = im[512 + t];
  float sn, cs;
  __sincosf(2.0f * PI_F * (float)t / 768.0f, &sn, &cs);
  float2 w1 = make_float2(cs, sn);
  float2 w2 = make_float2(cs * cs - sn * sn, 2.f * cs * sn);
  float b1r = a1r * w1.x - a1i * w1.y, b1i = a1r * w1.y + a1i * w1.x;
  float b2r = a2r * w2.x - a2i * w2.y, b2i = a2r * w2.y + a2i * w2.x;
  float Xr[3];
  Xr[0] = a0r + b1r + b2r;
  Xr[1] = a0r + (-0.5f * b1r - S3 * b1i) + (-0.5f * b2r + S3 * b2i);
  Xr[2] = a0r + (-0.5f * b1r + S3 * b1i) + (-0.5f * b2r - S3 * b2i);
  size_t ob = ((size_t)a * (LTOK + 1) + 1 + i) * DDIM + t;
  const float inv = 1.0f / 768.0f;
  out[ob]       = Xr[0] * inv;
  out[ob + 256] = Xr[1] * inv;
  out[ob + 512] = Xr[2] * inv;
}

// ---------------------------------------------------------------------------
extern "C" void kernel_launch(void* const* d_in, const int* in_sizes, int n_in,
                              void* d_out, int out_size, void* d_ws, size_t ws_size,
                              hipStream_t stream) {
  (void)in_sizes; (void)n_in; (void)out_size; (void)ws_size;
  const float* x    = (const float*)d_in[0];   // (2,197,768)
  const float* imgs = (const float*)d_in[1];   // (2,3,224,224)
  const float* ls   = (const float*)d_in[2];   // (2,196,196,1)
  const float* nz   = (const float*)d_in[3];   // (2,196,196,1)
  float* out = (float*)d_out;                  // (2,197,768)

  float* wf   = (float*)d_ws;
  float* u    = wf;                        // row-major 392 x 768
  float* sty  = wf + (size_t)NLD;
  float* phre = wf + 2 * (size_t)NLD;
  float* phim = wf + 3 * (size_t)NLD;
  float* savg = wf + 4 * (size_t)NLD;
  float* sstd = wf + 5 * (size_t)NLD;
  float* smsk = wf + 6 * (size_t)NLD;
  float* numP = wf + 7 * (size_t)NLD;      // 4 x NLD
  float* denP = wf + 11 * (size_t)NLD;     // 4 x NLD
  u64* Mb = (u64*)(wf + 15 * (size_t)NLD); // 1568 u64
  unsigned int* counter = (unsigned int*)(Mb + NROWS * 4);

  k_pre  <<<2 * NROWS + NBATCH, 256, 0, stream>>>(imgs, x, u, sty, phre, phim, out, Mb, counter);
  k_sim  <<<NSIMBLK, 256, 0, stream>>>(u, Mb, counter);
  k_stats<<<NROWS, 256, 0, stream>>>(Mb, sty, savg, sstd, smsk);
  k_comb <<<NBATCH * 28 * 3 * JCH, 256, 0, stream>>>(ls, nz, savg, sstd, smsk, numP, denP);
  k_ifft <<<NROWS, 256, 0, stream>>>(numP, denP, phre, phim, out);
}

// Round 9
// 134.595 us; speedup vs baseline: 3.2378x; 1.0243x over previous
//
#include <hip/hip_runtime.h>
#include <math.h>

typedef unsigned long long u64;

#define NBATCH 2
#define LTOK 196
#define DDIM 768
#define NROWS (NBATCH*LTOK)      // 392
#define NLD (NBATCH*LTOK*DDIM)   // 301056

#define PI_F 3.14159265358979323846f
#define S3 0.86602540378443864676f   // sqrt(3)/2

// combine tiling: 2(a) x 28(i-tile of 7) x 3(d-chunk) x 4(j-chunk of 49) = 672 blocks
#define RT 7
#define JCH 4
#define JLEN 49

// sim tiling: 7 i-tiles of 32; upper-triangle pairs = 28; x2 batches = 56 blocks
#define NSIMBLK (2 * 28)

// ---------------------------------------------------------------------------
// FFT768 = 3 x FFT256 (radix-2 DIT, bit-reversed in-place) + radix-3 combine.
// ---------------------------------------------------------------------------
__device__ __forceinline__ void fft_butterfly(float* re, float* im,
                                              const float2* T,
                                              int tau, int s, int half) {
  int sub = tau >> 7;            // 0..2
  int b = tau & 127;
  int j = b & (half - 1);
  int p0 = (sub << 8) + ((b >> (s - 1)) << s) + j;
  int p1 = p0 + half;
  float2 w = T[j << (8 - s)];
  float xr = re[p1], xi = im[p1];
  float tr = w.x * xr - w.y * xi;
  float ti = w.x * xi + w.y * xr;
  float ur = re[p0], ui = im[p0];
  re[p0] = ur + tr; im[p0] = ui + ti;
  re[p1] = ur - tr; im[p1] = ui - ti;
}

__device__ __forceinline__ void fft_stages(float* re, float* im,
                                           const float2* T, int t) {
#pragma unroll
  for (int s = 1; s <= 8; s++) {
    int half = 1 << (s - 1);
    fft_butterfly(re, im, T, t, s, half);
    if (t < 128) fft_butterfly(re, im, T, t + 256, s, half);
    __syncthreads();
  }
}

// ---------------------------------------------------------------------------
// K1 "pre": blocks [0,392)   patchify+standardize -> u (row-major)
//           blocks [392,784) forward FFT of x rows -> sty, phase
//           blocks [784,786) cls-token copy; block 784 zeroes counter + Mb
// ---------------------------------------------------------------------------
__global__ __launch_bounds__(256) void k_pre(const float* __restrict__ imgs,
                                             const float* __restrict__ x,
                                             float* __restrict__ u,
                                             float* __restrict__ sty,
                                             float* __restrict__ phre,
                                             float* __restrict__ phim,
                                             float* __restrict__ out,
                                             u64* __restrict__ Mb,
                                             unsigned int* __restrict__ counter) {
  int t = threadIdx.x;
  if (blockIdx.x >= 2 * NROWS) {            // cls rows + zero Mb/counter
    int a = blockIdx.x - 2 * NROWS;
    if (a == 0) {
      if (t == 0) *counter = 0u;
      for (int w = t; w < NROWS * 4; w += 256) Mb[w] = 0ull;
    }
    size_t b = (size_t)a * (LTOK + 1) * DDIM;
    out[b + t] = x[b + t];
    out[b + t + 256] = x[b + t + 256];
    out[b + t + 512] = x[b + t + 512];
    return;
  }
  if (blockIdx.x < NROWS) {
    // ---- patch branch ----
    int blk = blockIdx.x;
    int a = blk / LTOK, l = blk - a * LTOK;
    int hh = l / 14, ww = l - hh * 14;
    int p = t >> 4, q = t & 15;
    float loc[3];
    double s = 0.0, sq = 0.0;
#pragma unroll
    for (int c = 0; c < 3; c++) {
      float val = imgs[((size_t)(a * 3 + c) * 224 + (hh * 16 + p)) * 224 + (ww * 16 + q)];
      loc[c] = val;
      s += (double)val;
      sq += (double)val * (double)val;
    }
#pragma unroll
    for (int o = 32; o > 0; o >>= 1) { s += __shfl_down(s, o); sq += __shfl_down(sq, o); }
    __shared__ double rs[4], rq[4];
    __shared__ float sh_mu, sh_sc;
    if ((t & 63) == 0) { rs[t >> 6] = s; rq[t >> 6] = sq; }
    __syncthreads();
    if (t == 0) {
      double S = rs[0] + rs[1] + rs[2] + rs[3];
      double Q = rq[0] + rq[1] + rq[2] + rq[3];
      double mean = S / 768.0;
      double ss = Q - S * S / 768.0;
      if (ss < 1e-30) ss = 1e-30;
      sh_mu = (float)mean;
      sh_sc = (float)(1.0 / sqrt(ss));
    }
    __syncthreads();
    float mu = sh_mu, sc = sh_sc;
    size_t rbase = ((size_t)(a * LTOK + l)) * DDIM;
#pragma unroll
    for (int c = 0; c < 3; c++) {
      int d = 3 * t + c;
      u[rbase + d] = (loc[c] - mu) * sc;
    }
  } else {
    // ---- forward FFT branch ----
    int blk = blockIdx.x - NROWS;
    int a = blk / LTOK, i = blk - a * LTOK;
    __shared__ float re[768], im[768];
    __shared__ float2 t256[128];    // e^{-2pi i q/256}
    if (t < 128) {
      float sn, cs;
      __sincosf(-2.0f * PI_F * (float)t / 256.0f, &sn, &cs);
      t256[t] = make_float2(cs, sn);
    }
    size_t row = ((size_t)a * (LTOK + 1) + 1 + i) * DDIM;
#pragma unroll
    for (int e = 0; e < 3; e++) {
      int d = t + (e << 8);
      int m = d / 3, r = d - 3 * m;          // decimate n = 3m + r
      int p = (r << 8) + (__brev((unsigned)m) >> 24);
      re[p] = x[row + d];
      im[p] = 0.f;
    }
    __syncthreads();
    fft_stages(re, im, t256, t);
    float a0r = re[t],       a0i = im[t];
    float a1r = re[256 + t], a1i = im[256 + t];
    float a2r = re[512 + t], a2i = im[512 + t];
    float sn, cs;
    __sincosf(-2.0f * PI_F * (float)t / 768.0f, &sn, &cs);
    float2 w1 = make_float2(cs, sn);
    float2 w2 = make_float2(cs * cs - sn * sn, 2.f * cs * sn);
    float b1r = a1r * w1.x - a1i * w1.y, b1i = a1r * w1.y + a1i * w1.x;
    float b2r = a2r * w2.x - a2i * w2.y, b2i = a2r * w2.y + a2i * w2.x;
    float Xr[3], Xi[3];
    Xr[0] = a0r + b1r + b2r;
    Xi[0] = a0i + b1i + b2i;
    Xr[1] = a0r + (-0.5f * b1r + S3 * b1i) + (-0.5f * b2r - S3 * b2i);
    Xi[1] = a0i + (-0.5f * b1i - S3 * b1r) + (-0.5f * b2i + S3 * b2r);
    Xr[2] = a0r + (-0.5f * b1r - S3 * b1i) + (-0.5f * b2r + S3 * b2i);
    Xi[2] = a0i + (-0.5f * b1i + S3 * b1r) + (-0.5f * b2i - S3 * b2r);
    size_t ob = ((size_t)a * LTOK + i) * DDIM + t;
#pragma unroll
    for (int s = 0; s < 3; s++) {
      float mag = sqrtf(Xr[s] * Xr[s] + Xi[s] * Xi[s]);
      size_t o = ob + (s << 8);
      sty[o] = mag;
      if (mag > 0.f) { phre[o] = Xr[s] / mag; phim[o] = Xi[s] / mag; }
      else           { phre[o] = 1.f;         phim[o] = 0.f;         }
    }
  }
}

// ---------------------------------------------------------------------------
// K2: tiled-GEMM Sim. 56 blocks: (a, upper-tri 32x32 tile pair). Each thread
// accumulates a 2x2 register tile over K=768 staged in k-major LDS (padded).
// Bits (Sim>0.3, j>=i) atomicOr'd into zeroed Mb. Last block (device counter)
// runs the faithful sequential greedy loop in LDS.
// ---------------------------------------------------------------------------
union SimSMem {
  struct { float As[32][34]; float Bs[32][34]; } gemm;          // 8704 B
  struct { u64 Ml[NROWS * 4]; int red[4]; int done; } greedy;   // 12564 B
};

__global__ __launch_bounds__(256) void k_sim(const float* __restrict__ u,
                                             u64* __restrict__ Mb,
                                             unsigned int* __restrict__ counter) {
  __shared__ SimSMem sm;
  __shared__ int s_last;
  int t = threadIdx.x;
  {
    int a = blockIdx.x / 28;
    int p = blockIdx.x - a * 28;
    int it = 0;
    while (p >= 7 - it) { p -= 7 - it; it++; }
    int jt = it + p;
    int i0 = it << 5, j0 = jt << 5;
    int ty = t >> 4, tx = t & 15;
    int r = t >> 3;                 // 0..31
    int kq = (t & 7) << 2;          // 0,4,...,28
    float c00 = 0.f, c01 = 0.f, c10 = 0.f, c11 = 0.f;
    for (int k0 = 0; k0 < DDIM; k0 += 32) {
      {
        int row = i0 + r;
        float4 v = make_float4(0.f, 0.f, 0.f, 0.f);
        if (row < LTOK) v = *(const float4*)(u + ((size_t)(a * LTOK + row)) * DDIM + k0 + kq);
        sm.gemm.As[kq + 0][r] = v.x; sm.gemm.As[kq + 1][r] = v.y;
        sm.gemm.As[kq + 2][r] = v.z; sm.gemm.As[kq + 3][r] = v.w;
      }
      {
        int row = j0 + r;
        float4 v = make_float4(0.f, 0.f, 0.f, 0.f);
        if (row < LTOK) v = *(const float4*)(u + ((size_t)(a * LTOK + row)) * DDIM + k0 + kq);
        sm.gemm.Bs[kq + 0][r] = v.x; sm.gemm.Bs[kq + 1][r] = v.y;
        sm.gemm.Bs[kq + 2][r] = v.z; sm.gemm.Bs[kq + 3][r] = v.w;
      }
      __syncthreads();
#pragma unroll
      for (int k = 0; k < 32; k++) {
        float2 av = *(const float2*)&sm.gemm.As[k][ty << 1];
        float2 bv = *(const float2*)&sm.gemm.Bs[k][tx << 1];
        c00 += av.x * bv.x; c01 += av.x * bv.y;
        c10 += av.y * bv.x; c11 += av.y * bv.y;
      }
      __syncthreads();
    }
    float cc[2][2] = {{c00, c01}, {c10, c11}};
#pragma unroll
    for (int ii = 0; ii < 2; ii++) {
#pragma unroll
      for (int jj = 0; jj < 2; jj++) {
        int i = i0 + (ty << 1) + ii;
        int j = j0 + (tx << 1) + jj;
        if (i < LTOK && j < LTOK && j >= i && cc[ii][jj] > 0.3f)
          atomicOr(&Mb[((size_t)(a * LTOK + i)) * 4 + (j >> 6)], 1ull << (j & 63));
      }
    }
  }
  __syncthreads();
  if (t == 0) {
    __threadfence();         // device-scope release of our Mb bits
    unsigned prev = atomicAdd(counter, 1u);
    s_last = (prev == NSIMBLK - 1) ? 1 : 0;
  }
  __syncthreads();
  if (!s_last) return;

  // ---------------- greedy (last block only) ----------------
  __threadfence();           // acquire
  for (int w = t; w < NROWS * 4; w += 256)
    sm.greedy.Ml[w] = __hip_atomic_load(&Mb[w], __ATOMIC_ACQUIRE, __HIP_MEMORY_SCOPE_AGENT);
  __syncthreads();
  for (int i = 0; i < LTOK - 1; i++) {
    int s = 0;
    for (int w = t; w < NROWS * 4; w += 256) s += __popcll(sm.greedy.Ml[w]);
#pragma unroll
    for (int o = 32; o > 0; o >>= 1) s += __shfl_down(s, o);
    if ((t & 63) == 0) sm.greedy.red[t >> 6] = s;
    __syncthreads();
    if (t == 0)
      sm.greedy.done = ((sm.greedy.red[0] + sm.greedy.red[1] +
                         sm.greedy.red[2] + sm.greedy.red[3]) == NROWS) ? 1 : 0;
    __syncthreads();
    if (sm.greedy.done) break;
    for (int w = t; w < NROWS * 4; w += 256) {
      int a = w / (LTOK * 4);
      int rem = w - a * (LTOK * 4);
      int r = rem >> 2, wi = rem & 3;
      if (r > i) sm.greedy.Ml[w] &= ~sm.greedy.Ml[(a * LTOK + i) * 4 + wi];
    }
    __syncthreads();
  }
  for (int w = t; w < NROWS * 4; w += 256) Mb[w] = sm.greedy.Ml[w];
}

// ---------------------------------------------------------------------------
// K3: masked stats per row — gather coalesced across threads (sr[t]); serial
//     chain only over mask bits. Writes packed float4 (mask*avg, mask*std,
//     mask, 0) per (row, d) -> one dwordx4 store / load downstream.
// ---------------------------------------------------------------------------
__global__ __launch_bounds__(256) void k_stats(const u64* __restrict__ Mb,
                                               const float* __restrict__ sty,
                                               float4* __restrict__ sab) {
  int blk = blockIdx.x;
  int a = blk / LTOK, i = blk - a * LTOK;
  __shared__ u64 mrow[4];
  int t = threadIdx.x;
  if (t < 4) mrow[t] = Mb[((size_t)a * LTOK + i) * 4 + t];
  __syncthreads();
  int num = __popcll(mrow[0]) + __popcll(mrow[1]) + __popcll(mrow[2]) + __popcll(mrow[3]);
  float fnum = fmaxf((float)num, 1e-7f);
  float acc0 = 0.f, acc1 = 0.f, acc2 = 0.f;
  for (int w = 0; w < 4; w++) {
    u64 m = mrow[w];
    while (m) {
      int b = __ffsll(m) - 1; m &= (m - 1);
      int j = (w << 6) + b;
      const float* sr = sty + ((size_t)a * LTOK + j) * DDIM;
      acc0 += sr[t]; acc1 += sr[t + 256]; acc2 += sr[t + 512];
    }
  }
  float av0 = acc0 / fnum, av1 = acc1 / fnum, av2 = acc2 / fnum;
  float sq0 = 0.f, sq1 = 0.f, sq2 = 0.f;
  for (int w = 0; w < 4; w++) {
    u64 m = mrow[w];
    while (m) {
      int b = __ffsll(m) - 1; m &= (m - 1);
      int j = (w << 6) + b;
      const float* sr = sty + ((size_t)a * LTOK + j) * DDIM;
      float d0 = sr[t] - av0, d1 = sr[t + 256] - av1, d2 = sr[t + 512] - av2;
      sq0 += d0 * d0; sq1 += d1 * d1; sq2 += d2 * d2;
    }
  }
  size_t o = ((size_t)a * LTOK + i) * DDIM + t;
  float mk0 = acc0 > 0.f ? 1.f : 0.f;
  float mk1 = acc1 > 0.f ? 1.f : 0.f;
  float mk2 = acc2 > 0.f ? 1.f : 0.f;
  sab[o]       = make_float4(mk0 * av0, mk0 * sqrtf(sq0 / fnum), mk0, 0.f);
  sab[o + 256] = make_float4(mk1 * av1, mk1 * sqrtf(sq1 / fnum), mk1, 0.f);
  sab[o + 512] = make_float4(mk2 * av2, mk2 * sqrtf(sq2 / fnum), mk2, 0.f);
}

// ---------------------------------------------------------------------------
// K4: combine partials. grid = 2*28*3*4 = 672 blocks. One dwordx4 stats load
//     per j, one dwordx2 (num,den) store per i-row.
// ---------------------------------------------------------------------------
__global__ __launch_bounds__(256) void k_comb(const float* __restrict__ ls,
                                              const float* __restrict__ nz,
                                              const float4* __restrict__ sab,
                                              float2* __restrict__ pd) {
  int blk = blockIdx.x;
  int a = blk / 336;
  int rem = blk - a * 336;
  int it = rem / 12;
  int r2 = rem - it * 12;
  int dc = r2 >> 2;
  int jc = r2 & 3;
  int i0 = it * RT;
  int j0 = jc * JLEN;
  int t = threadIdx.x;
  int d = (dc << 8) + t;
  __shared__ float lsr[RT][JLEN], lnr[RT][JLEN];
  for (int idx = t; idx < RT * JLEN; idx += 256) {
    int ii = idx / JLEN, j = idx - ii * JLEN;
    size_t o = ((size_t)(a * LTOK + i0 + ii)) * LTOK + j0 + j;
    float l = ls[o];
    lsr[ii][j] = l;
    lnr[ii][j] = l * nz[o];
  }
  __syncthreads();
  float nm[RT], dn[RT];
#pragma unroll
  for (int ii = 0; ii < RT; ii++) { nm[ii] = 0.f; dn[ii] = 0.f; }
#pragma unroll 7
  for (int j = 0; j < JLEN; j++) {
    float4 v = sab[((size_t)(a * LTOK + j0 + j)) * DDIM + d];   // (mav, msd, smv, 0)
#pragma unroll
    for (int ii = 0; ii < RT; ii++) {
      nm[ii] += lnr[ii][j] * v.y;
      nm[ii] += lsr[ii][j] * v.x;
      dn[ii] += lsr[ii][j] * v.z;
    }
  }
#pragma unroll
  for (int ii = 0; ii < RT; ii++) {
    size_t o = ((size_t)jc * NROWS + (a * LTOK + i0 + ii)) * DDIM + d;
    pd[o] = make_float2(nm[ii], dn[ii]);
  }
}

// ---------------------------------------------------------------------------
// K5: reduce 4 (num,den) partials -> ssum, inverse FFT, real part, /768.
// ---------------------------------------------------------------------------
__global__ __launch_bounds__(256) void k_ifft(const float2* __restrict__ pd,
                                              const float* __restrict__ phre,
                                              const float* __restrict__ phim,
                                              float* __restrict__ out) {
  int rr = blockIdx.x;
  int t = threadIdx.x;
  int a = rr / LTOK, i = rr - a * LTOK;
  __shared__ float re[768], im[768];
  __shared__ float2 t256[128];    // e^{+2pi i q/256}
  if (t < 128) {
    float sn, cs;
    __sincosf(2.0f * PI_F * (float)t / 256.0f, &sn, &cs);
    t256[t] = make_float2(cs, sn);
  }
  size_t rowz = ((size_t)a * LTOK + i) * DDIM;
#pragma unroll
  for (int e = 0; e < 3; e++) {
    int d = t + (e << 8);
    float num = 0.f, den = 0.f;
#pragma unroll
    for (int jc = 0; jc < JCH; jc++) {
      float2 v = pd[(size_t)jc * NROWS * DDIM + rowz + d];
      num += v.x;
      den += v.y;
    }
    float mg = num / fmaxf(den, 1e-7f);
    int m = d / 3, r = d - 3 * m;          // decimate k = 3m + r
    int p = (r << 8) + (__brev((unsigned)m) >> 24);
    re[p] = mg * phre[rowz + d];
    im[p] = mg * phim[rowz + d];
  }
  __syncthreads();
  fft_stages(re, im, t256, t);
  float a0r = re[t],       a0i = im[t];
  float a1r = re[256 + t], a1i = im[256 + t];
  float a2r = re[512 + t], a2i = im[512 + t];
  float sn, cs;
  __sincosf(2.0f * PI_F * (float)t / 768.0f, &sn, &cs);
  float2 w1 = make_float2(cs, sn);
  float2 w2 = make_float2(cs * cs - sn * sn, 2.f * cs * sn);
  float b1r = a1r * w1.x - a1i * w1.y, b1i = a1r * w1.y + a1i * w1.x;
  float b2r = a2r * w2.x - a2i * w2.y, b2i = a2r * w2.y + a2i * w2.x;
  float Xr[3];
  Xr[0] = a0r + b1r + b2r;
  Xr[1] = a0r + (-0.5f * b1r - S3 * b1i) + (-0.5f * b2r + S3 * b2i);
  Xr[2] = a0r + (-0.5f * b1r + S3 * b1i) + (-0.5f * b2r - S3 * b2i);
  size_t ob = ((size_t)a * (LTOK + 1) + 1 + i) * DDIM + t;
  const float inv = 1.0f / 768.0f;
  out[ob]       = Xr[0] * inv;
  out[ob + 256] = Xr[1] * inv;
  out[ob + 512] = Xr[2] * inv;
}

// ---------------------------------------------------------------------------
extern "C" void kernel_launch(void* const* d_in, const int* in_sizes, int n_in,
                              void* d_out, int out_size, void* d_ws, size_t ws_size,
                              hipStream_t stream) {
  (void)in_sizes; (void)n_in; (void)out_size; (void)ws_size;
  const float* x    = (const float*)d_in[0];   // (2,197,768)
  const float* imgs = (const float*)d_in[1];   // (2,3,224,224)
  const float* ls   = (const float*)d_in[2];   // (2,196,196,1)
  const float* nz   = (const float*)d_in[3];   // (2,196,196,1)
  float* out = (float*)d_out;                  // (2,197,768)

  float* wf    = (float*)d_ws;
  float* u     = wf;                        // row-major 392 x 768
  float* sty   = wf + (size_t)NLD;
  float* phre  = wf + 2 * (size_t)NLD;
  float* phim  = wf + 3 * (size_t)NLD;
  float4* sab  = (float4*)(wf + 4 * (size_t)NLD);   // NLD float4 = 4 x NLD floats
  float2* pd   = (float2*)(wf + 8 * (size_t)NLD);   // 4 x NLD float2 = 8 x NLD floats
  u64* Mb = (u64*)(wf + 16 * (size_t)NLD);          // 1568 u64
  unsigned int* counter = (unsigned int*)(Mb + NROWS * 4);

  k_pre  <<<2 * NROWS + NBATCH, 256, 0, stream>>>(imgs, x, u, sty, phre, phim, out, Mb, counter);
  k_sim  <<<NSIMBLK, 256, 0, stream>>>(u, Mb, counter);
  k_stats<<<NROWS, 256, 0, stream>>>(Mb, sty, sab);
  k_comb <<<NBATCH * 28 * 3 * JCH, 256, 0, stream>>>(ls, nz, sab, pd);
  k_ifft <<<NROWS, 256, 0, stream>>>(pd, phre, phim, out);
}